// Round 6
// baseline (186.687 us; speedup 1.0000x reference)
//
#include <hip/hip_runtime.h>

#define NPTS 8192
#define NSLICE 64
#define SLICE_LEN (NPTS / NSLICE)
#define KNN 8
#define SURV_CAP 32

typedef short bf16x8 __attribute__((ext_vector_type(8)));
typedef float f32x4 __attribute__((ext_vector_type(4)));

// bf16 round-to-nearest-even split helpers.
__device__ __forceinline__ unsigned short f2bf(float x) {
  unsigned int u = __float_as_uint(x);
  return (unsigned short)((u + 0x7FFF + ((u >> 16) & 1)) >> 16);
}
__device__ __forceinline__ float bf2f(unsigned short s) {
  return __uint_as_float(((unsigned int)s) << 16);
}

// Distance helpers. contract(off) pins the value DAG (r3 failure lesson);
// both vals and collect consume IDENTICAL pts4 inputs, so distances are
// bit-identical across kernels; inflated thresholds add a second safety net.
__device__ __forceinline__ float dist_exact(float qx, float qy, float qz,
                                            float q2, float px, float py,
                                            float pz, float p2) {
#pragma clang fp contract(off)
  float dot = __fmaf_rn(qz, pz, __fmaf_rn(qy, py, __fmul_rn(qx, px)));
  float t1 = __fadd_rn(q2, p2);
  return __fadd_rn(t1, __fmul_rn(-2.0f, dot));
}

__device__ __forceinline__ float norm2_exact(float x, float y, float z) {
#pragma clang fp contract(off)
  return __fadd_rn(__fadd_rn(__fmul_rn(x, x), __fmul_rn(y, y)),
                   __fmul_rn(z, z));
}

__device__ __forceinline__ float med3(float a, float b, float c) {
  return __builtin_amdgcn_fmed3f(a, b, c);
}

// Monotone (d, idx) -> f64 key (used only in the tiny final sort).
__device__ __forceinline__ double pack_key(float d, int idx) {
  unsigned int ub = __float_as_uint(d);
  ub ^= (((unsigned int)((int)ub >> 31)) | 0x80000000u);
  unsigned int lo = (ub << 13) | (unsigned int)idx;
  unsigned int hi = 0x3ff00000u | (ub >> 19);
  return __hiloint2double((int)hi, (int)lo);
}

#define KEY_DECL                                                            \
  const double KINF = __longlong_as_double(0x7ff0000000000000LL);           \
  double k0 = KINF, k1 = KINF, k2 = KINF, k3 = KINF, k4 = KINF, k5 = KINF,  \
         k6 = KINF, k7 = KINF;
#define KB1(s)                                                              \
  {                                                                         \
    double mn = fmin(carry, k##s);                                          \
    carry = fmax(carry, k##s);                                              \
    k##s = mn;                                                              \
  }
#define KEY_INSERT(key)                                                     \
  {                                                                         \
    double carry = (key);                                                   \
    KB1(0) KB1(1) KB1(2) KB1(3) KB1(4) KB1(5) KB1(6) KB1(7)                 \
  }

// f32 value-only sorted-8 insert: 7 med3 + 1 min, in-place descending
// (each stage reads only not-yet-updated lower regs).
#define VINS(dv)                                                            \
  {                                                                         \
    float dd = (dv);                                                        \
    v7 = med3(dd, v6, v7);                                                  \
    v6 = med3(dd, v5, v6);                                                  \
    v5 = med3(dd, v4, v5);                                                  \
    v4 = med3(dd, v3, v4);                                                  \
    v3 = med3(dd, v2, v3);                                                  \
    v2 = med3(dd, v1, v2);                                                  \
    v1 = med3(dd, v0, v1);                                                  \
    v0 = fminf(dd, v0);                                                     \
  }

#define VDECL                                                               \
  const float FINF = __uint_as_float(0x7f800000u);                          \
  float v0 = FINF, v1 = FINF, v2 = FINF, v3 = FINF, v4 = FINF, v5 = FINF,   \
        v6 = FINF, v7 = FINF;

// ---------------------------------------------------------------------------
// Pack pts -> float4 (x,y,z,norm2). Single source of norm bits for vals AND
// collect (removes the last cross-kernel bit-divergence source).
// ---------------------------------------------------------------------------
__global__ __launch_bounds__(256) void pack_pts4_kernel(
    const float* __restrict__ pts, float4* __restrict__ pts4) {
  const int j = blockIdx.x * 256 + threadIdx.x;
  float x = pts[j * 3 + 0];
  float y = pts[j * 3 + 1];
  float z = pts[j * 3 + 2];
  pts4[j] = make_float4(x, y, z, norm2_exact(x, y, z));
}

// ---------------------------------------------------------------------------
// KNN A: per (query, slice of 128) keep 8 smallest DISTANCE VALUES (f32).
// Candidates are WAVE-UNIFORM: read pts4 at uniform addresses -> compiler
// promotes to s_load (scalar pipe, constant cache). No LDS, no barrier.
// Output transposed for coalescing: part_v[(slice*8+rank)*NPTS + q].
// Ranks of one slice are ASCENDING (v0..v7 sorted) -- collect relies on it.
// ---------------------------------------------------------------------------
__global__ __launch_bounds__(256) void knn_vals_kernel(
    const float4* __restrict__ pts4, float* __restrict__ part_v) {
  const int t = threadIdx.x;
  const int q = blockIdx.x * 256 + t;
  const int jbase = blockIdx.y * SLICE_LEN;
  const float4 qp = pts4[q];
  const float qx = qp.x, qy = qp.y, qz = qp.z, q2 = qp.w;
  VDECL;
  for (int p = 0; p < SLICE_LEN; p += 8) {
    float4 c0 = pts4[jbase + p + 0];
    float4 c1 = pts4[jbase + p + 1];
    float4 c2 = pts4[jbase + p + 2];
    float4 c3 = pts4[jbase + p + 3];
    float4 c4 = pts4[jbase + p + 4];
    float4 c5 = pts4[jbase + p + 5];
    float4 c6 = pts4[jbase + p + 6];
    float4 c7 = pts4[jbase + p + 7];
    float d0 = dist_exact(qx, qy, qz, q2, c0.x, c0.y, c0.z, c0.w);
    float d1 = dist_exact(qx, qy, qz, q2, c1.x, c1.y, c1.z, c1.w);
    float d2 = dist_exact(qx, qy, qz, q2, c2.x, c2.y, c2.z, c2.w);
    float d3 = dist_exact(qx, qy, qz, q2, c3.x, c3.y, c3.z, c3.w);
    float d4 = dist_exact(qx, qy, qz, q2, c4.x, c4.y, c4.z, c4.w);
    float d5 = dist_exact(qx, qy, qz, q2, c5.x, c5.y, c5.z, c5.w);
    float d6 = dist_exact(qx, qy, qz, q2, c6.x, c6.y, c6.z, c6.w);
    float d7 = dist_exact(qx, qy, qz, q2, c7.x, c7.y, c7.z, c7.w);
    VINS(d0);
    VINS(d1);
    VINS(d2);
    VINS(d3);
    VINS(d4);
    VINS(d5);
    VINS(d6);
    VINS(d7);
  }
  float* o = &part_v[(size_t)(blockIdx.y * 8) * NPTS + q];
  o[0 * NPTS] = v0;
  o[1 * NPTS] = v1;
  o[2 * NPTS] = v2;
  o[3 * NPTS] = v3;
  o[4 * NPTS] = v4;
  o[5 * NPTS] = v5;
  o[6 * NPTS] = v6;
  o[7 * NPTS] = v7;
}

// ---------------------------------------------------------------------------
// KNN B (fused thresh+collect+final): one WAVE per query.
// Phase 1: lane l loads slice l's sorted 8 ranks from part_v.
// Phase 2: 8x wave extract-min (shfl reduce + ballot leader-advance) ->
//          exact global 8th-smallest m (multiset semantics == VINS merge).
//          Inflated thresholds: tcol=m*(1+4e-5) gate, tmask=m*(1+8e-5);
//          slice mask = __ballot(slice_min <= tmask) (<=~8 bits set).
// Phase 3: scan marked slices (~1k candidates, not 8192); survivors
//          (d<=tcol, ~8-10) -> LDS keybuf via LDS atomics; lane 0 sorts the
//          f64 (d,idx) keys and writes nbr. Self-consistent selection ==
//          jax.lax.top_k order (ties at m break by lowest index).
// ---------------------------------------------------------------------------
__global__ __launch_bounds__(256) void knn_collect_kernel(
    const float4* __restrict__ pts4, const float* __restrict__ part_v,
    int* __restrict__ nbr) {
  __shared__ double keybuf[4][SURV_CAP];
  __shared__ int scnt[4];
  const int t = threadIdx.x;
  const int wv = t >> 6;
  const int lane = t & 63;
  const int q = blockIdx.x * 4 + wv;
  if (lane == 0) scnt[wv] = 0;
  __syncthreads();

  // Phase 1: this lane's slice ranks (already ascending).
  const float FINF = __uint_as_float(0x7f800000u);
  const float* col = &part_v[(size_t)(lane * 8) * NPTS + q];
  float r0 = col[0 * (size_t)NPTS];
  float r1 = col[1 * (size_t)NPTS];
  float r2 = col[2 * (size_t)NPTS];
  float r3 = col[3 * (size_t)NPTS];
  float r4 = col[4 * (size_t)NPTS];
  float r5 = col[5 * (size_t)NPTS];
  float r6 = col[6 * (size_t)NPTS];
  float r7 = col[7 * (size_t)NPTS];
  const float smin0 = r0;

  // Phase 2: 8x extract-min across the wave.
  float m = FINF;
#pragma unroll
  for (int it = 0; it < 8; ++it) {
    float h = r0;
#pragma unroll
    for (int off = 32; off; off >>= 1) h = fminf(h, __shfl_xor(h, off, 64));
    m = h;
    unsigned long long ball = __ballot(r0 == h);
    int leader = (int)__ffsll(ball) - 1;
    if (lane == leader) {
      r0 = r1; r1 = r2; r2 = r3; r3 = r4;
      r4 = r5; r5 = r6; r6 = r7; r7 = FINF;
    }
  }
  const float tcol = m + fabsf(m) * 4e-5f + 1e-20f;
  const float tmask = m + fabsf(m) * 8e-5f + 2e-20f;
  unsigned long long mask = __ballot(smin0 <= tmask);

  // Phase 3: scan marked slices.
  const float4 qp = pts4[q];
  const float qx = qp.x, qy = qp.y, qz = qp.z, q2 = qp.w;
  unsigned long long mm = mask;
  while (mm) {
    const int s = (int)__ffsll(mm) - 1;
    mm &= mm - 1;
    const int base = s * SLICE_LEN;
#pragma unroll
    for (int r = 0; r < SLICE_LEN / 64; ++r) {
      const int j = base + r * 64 + lane;
      const float4 cp = pts4[j];
      const float d = dist_exact(qx, qy, qz, q2, cp.x, cp.y, cp.z, cp.w);
      if (d <= tcol) {
        int slot = atomicAdd(&scnt[wv], 1);
        if (slot < SURV_CAP) keybuf[wv][slot] = pack_key(d, j);
      }
    }
  }
  __syncthreads();
  if (lane == 0) {
    int c = scnt[wv];
    if (c > SURV_CAP) c = SURV_CAP;
    KEY_DECL;
    for (int u = 0; u < c; ++u) {
      KEY_INSERT(keybuf[wv][u]);
    }
    int* o = &nbr[q * KNN];
    o[0] = __double2loint(k0) & 0x1fff;
    o[1] = __double2loint(k1) & 0x1fff;
    o[2] = __double2loint(k2) & 0x1fff;
    o[3] = __double2loint(k3) & 0x1fff;
    o[4] = __double2loint(k4) & 0x1fff;
    o[5] = __double2loint(k5) & 0x1fff;
    o[6] = __double2loint(k6) & 0x1fff;
    o[7] = __double2loint(k7) & 0x1fff;
  }
}

// ---------------------------------------------------------------------------
// Fused EdgeConv1: H1 tile in LDS, GEMM W2, max8, +b2, relu -> y (8192x128).
// ---------------------------------------------------------------------------
__global__ __launch_bounds__(256) void gemm1_fused_kernel(
    const float* __restrict__ pts, const int* __restrict__ nbr,
    const float* __restrict__ W1, const float* __restrict__ b1,
    const float* __restrict__ W2, const float* __restrict__ b2,
    float* __restrict__ y) {
  __shared__ float es[64][6];
  __shared__ float W1s[6][64];
  __shared__ float b1s[64];
  __shared__ float As[64][64];
  __shared__ float Bs[64][64];
  const int t = threadIdx.x;
  const int rowBase = blockIdx.y * 64;
  const int colBase = blockIdx.x * 64;

  for (int idx = t; idx < 384; idx += 256) W1s[idx >> 6][idx & 63] = W1[idx];
  if (t < 64) b1s[t] = b1[t];
  {
    int cq = t & 15, kr = t >> 4;
#pragma unroll
    for (int it = 0; it < 4; ++it) {
      int k = it * 16 + kr;
      *(float4*)&Bs[k][cq * 4] =
          *(const float4*)&W2[(size_t)k * 128 + colBase + cq * 4];
    }
  }
  if (t < 64) {
    int e = rowBase + t;
    int i = e >> 3;
    int j = nbr[e];
    float xi0 = pts[i * 3], xi1 = pts[i * 3 + 1], xi2 = pts[i * 3 + 2];
    es[t][0] = xi0;
    es[t][1] = xi1;
    es[t][2] = xi2;
    es[t][3] = pts[j * 3] - xi0;
    es[t][4] = pts[j * 3 + 1] - xi1;
    es[t][5] = pts[j * 3 + 2] - xi2;
  }
  __syncthreads();

  {
    const int e = t & 63, k0 = (t >> 6) * 16;
    const float f0 = es[e][0], f1 = es[e][1], f2 = es[e][2];
    const float f3 = es[e][3], f4 = es[e][4], f5 = es[e][5];
#pragma unroll
    for (int k = 0; k < 16; ++k) {
      int c = k0 + k;
      float v = b1s[c];
      v = fmaf(f0, W1s[0][c], v);
      v = fmaf(f1, W1s[1][c], v);
      v = fmaf(f2, W1s[2][c], v);
      v = fmaf(f3, W1s[3][c], v);
      v = fmaf(f4, W1s[4][c], v);
      v = fmaf(f5, W1s[5][c], v);
      As[c][e] = fmaxf(v, 0.0f);
    }
  }
  __syncthreads();

  const int tx = t & 15, ty = t >> 4;
  float acc[4][4] = {};
#pragma unroll 8
  for (int k = 0; k < 64; ++k) {
    float4 a = *(const float4*)&As[k][ty * 4];
    float4 b = *(const float4*)&Bs[k][tx * 4];
    const float ar[4] = {a.x, a.y, a.z, a.w};
    const float br[4] = {b.x, b.y, b.z, b.w};
#pragma unroll
    for (int i = 0; i < 4; ++i)
#pragma unroll
      for (int jj = 0; jj < 4; ++jj)
        acc[i][jj] = fmaf(ar[i], br[jj], acc[i][jj]);
  }
  __syncthreads();

  float* Mx = &As[0][0];
#pragma unroll
  for (int jj = 0; jj < 4; ++jj) {
    float m =
        fmaxf(fmaxf(acc[0][jj], acc[1][jj]), fmaxf(acc[2][jj], acc[3][jj]));
    Mx[ty * 64 + tx * 4 + jj] = m;
  }
  __syncthreads();
  if (t < 128) {
    int p = t >> 4, cq = t & 15;
    int c = cq * 4;
    float4 o;
    float* oa = (float*)&o;
#pragma unroll
    for (int jj = 0; jj < 4; ++jj) {
      float v = fmaxf(Mx[(2 * p) * 64 + c + jj], Mx[(2 * p + 1) * 64 + c + jj]);
      v += b2[colBase + c + jj];
      oa[jj] = fmaxf(v, 0.0f);
    }
    *(float4*)&y[(size_t)(blockIdx.y * 8 + p) * 128 + colBase + c] = o;
  }
}

// Split W4 (128x256 fp32) into transposed bf16 hi/lo: W4ht/W4lt[col*128+k].
__global__ __launch_bounds__(256) void w4split_kernel(
    const float* __restrict__ W4, unsigned short* __restrict__ W4ht,
    unsigned short* __restrict__ W4lt) {
  const int id = blockIdx.x * 256 + threadIdx.x;  // 32768
  const int k = id >> 8, c = id & 255;
  float v = W4[k * 256 + c];
  unsigned short hi = f2bf(v);
  unsigned short lo = f2bf(v - bf2f(hi));
  W4ht[c * 128 + k] = hi;
  W4lt[c * 128 + k] = lo;
}

// ---------------------------------------------------------------------------
// AC = y @ [W3top|W3bot] (+b3 on cols<128). 64x64 GEMM (8192x128x256).
// B staged DIRECTLY from W3 (col band lies in one half of the concat).
// ---------------------------------------------------------------------------
__global__ __launch_bounds__(256) void gemm_ac_kernel(
    const float* __restrict__ A, const float* __restrict__ W3,
    const float* __restrict__ bias, float* __restrict__ out) {
  __shared__ float As[64][64];
  __shared__ float Bs[64][64];
  const int t = threadIdx.x;
  const int tx = t & 15, ty = t >> 4;
  const int rowBase = blockIdx.y * 64;
  const int colBase = blockIdx.x * 64;
  const float4* A4 = (const float4*)A;
  float acc[4][4] = {};
  const int K = 128, Nglob = 256;

  for (int k0 = 0; k0 < K; k0 += 64) {
#pragma unroll
    for (int it = 0; it < 4; ++it) {
      int idx = it * 256 + t;
      int row = idx & 63, kq = idx >> 6;
      float4 av = A4[(size_t)(rowBase + row) * (K >> 2) + (k0 >> 2) + kq];
      As[kq * 4 + 0][row] = av.x;
      As[kq * 4 + 1][row] = av.y;
      As[kq * 4 + 2][row] = av.z;
      As[kq * 4 + 3][row] = av.w;
    }
#pragma unroll
    for (int it = 0; it < 4; ++it) {
      int idx = it * 256 + t;
      int cq = idx & 15, kr = idx >> 4;
      const float* src =
          (colBase < 128)
              ? &W3[(size_t)(k0 + kr) * 128 + colBase]
              : &W3[(size_t)(128 + k0 + kr) * 128 + (colBase - 128)];
      float4 bv = *(const float4*)&src[cq * 4];
      *(float4*)&Bs[kr][cq * 4] = bv;
    }
    __syncthreads();
#pragma unroll 8
    for (int k = 0; k < 64; ++k) {
      float4 a = *(const float4*)&As[k][ty * 4];
      float4 b = *(const float4*)&Bs[k][tx * 4];
      const float ar[4] = {a.x, a.y, a.z, a.w};
      const float br[4] = {b.x, b.y, b.z, b.w};
#pragma unroll
      for (int i = 0; i < 4; ++i)
#pragma unroll
        for (int jj = 0; jj < 4; ++jj)
          acc[i][jj] = fmaf(ar[i], br[jj], acc[i][jj]);
    }
    __syncthreads();
  }

#pragma unroll
  for (int i = 0; i < 4; ++i) {
    float4 o;
    float* oa = (float*)&o;
#pragma unroll
    for (int jj = 0; jj < 4; ++jj) {
      float v = acc[i][jj];
      int cg = colBase + tx * 4 + jj;
      if (cg < 128) v += bias[cg];
      oa[jj] = v;
    }
    *(float4*)&out[(size_t)(rowBase + ty * 4 + i) * Nglob + colBase + tx * 4] =
        o;
  }
}

// ---------------------------------------------------------------------------
// MFMA EdgeConv2 second layer (split-bf16), as R7 (verified):
// D = Hh*Wh + Hh*Wl + Hl*Wh in fp32 MFMA acc; in-register segmax + b4.
// ---------------------------------------------------------------------------
__global__ __launch_bounds__(256) void gemm2_mfma_kernel(
    const float* __restrict__ AC, const int* __restrict__ nbr,
    const unsigned short* __restrict__ W4ht,
    const unsigned short* __restrict__ W4lt, const float* __restrict__ b4,
    float* __restrict__ out) {
  __shared__ unsigned short H2h[128 * 40];
  __shared__ unsigned short H2l[128 * 40];
  __shared__ unsigned short Wth[128 * 40];
  __shared__ unsigned short Wtl[128 * 40];
  const int t = threadIdx.x;
  const int rowBase = blockIdx.y * 128;
  const int colBase = blockIdx.x * 128;
  const int eloc = t >> 1, hh = t & 1;
  const int kb = hh * 16;
  const int edge = rowBase + eloc;
  const int ip = edge >> 3;
  const int jp = nbr[edge];
  const float* ai_p = AC + (size_t)ip * 256;
  const float* ci_p = ai_p + 128;
  const float* cj_p = AC + (size_t)jp * 256 + 128;
  const int lane = t & 63;
  const int w = t >> 6;
  const int q = lane >> 4;
  const int nidx = lane & 15;

  f32x4 acc[2][8];
#pragma unroll
  for (int mt = 0; mt < 2; ++mt)
#pragma unroll
    for (int nt = 0; nt < 8; ++nt) acc[mt][nt] = (f32x4){0.f, 0.f, 0.f, 0.f};

  for (int p = 0; p < 4; ++p) {
    const int k0 = p * 32;
    {
      float h2[16];
      const float4* a4 = (const float4*)(ai_p + k0 + kb);
      const float4* c4 = (const float4*)(ci_p + k0 + kb);
      const float4* d4 = (const float4*)(cj_p + k0 + kb);
#pragma unroll
      for (int u = 0; u < 4; ++u) {
        float4 a = a4[u], c = c4[u], d = d4[u];
        h2[u * 4 + 0] = fmaxf(a.x + d.x - c.x, 0.f);
        h2[u * 4 + 1] = fmaxf(a.y + d.y - c.y, 0.f);
        h2[u * 4 + 2] = fmaxf(a.z + d.z - c.z, 0.f);
        h2[u * 4 + 3] = fmaxf(a.w + d.w - c.w, 0.f);
      }
      unsigned int hp[8], lp[8];
#pragma unroll
      for (int u = 0; u < 8; ++u) {
        unsigned short h0 = f2bf(h2[2 * u]), h1 = f2bf(h2[2 * u + 1]);
        hp[u] = (unsigned int)h0 | ((unsigned int)h1 << 16);
        unsigned short l0 = f2bf(h2[2 * u] - bf2f(h0));
        unsigned short l1 = f2bf(h2[2 * u + 1] - bf2f(h1));
        lp[u] = (unsigned int)l0 | ((unsigned int)l1 << 16);
      }
      *(uint4*)&H2h[eloc * 40 + kb] = make_uint4(hp[0], hp[1], hp[2], hp[3]);
      *(uint4*)&H2h[eloc * 40 + kb + 8] =
          make_uint4(hp[4], hp[5], hp[6], hp[7]);
      *(uint4*)&H2l[eloc * 40 + kb] = make_uint4(lp[0], lp[1], lp[2], lp[3]);
      *(uint4*)&H2l[eloc * 40 + kb + 8] =
          make_uint4(lp[4], lp[5], lp[6], lp[7]);
    }
    {
      const size_t src = (size_t)(colBase + eloc) * 128 + k0 + kb;
      *(uint4*)&Wth[eloc * 40 + kb] = *(const uint4*)&W4ht[src];
      *(uint4*)&Wth[eloc * 40 + kb + 8] = *(const uint4*)&W4ht[src + 8];
      *(uint4*)&Wtl[eloc * 40 + kb] = *(const uint4*)&W4lt[src];
      *(uint4*)&Wtl[eloc * 40 + kb + 8] = *(const uint4*)&W4lt[src + 8];
    }
    __syncthreads();
    bf16x8 ah[2], al[2];
#pragma unroll
    for (int mt = 0; mt < 2; ++mt) {
      int row = w * 32 + mt * 16 + nidx;
      ah[mt] = *(const bf16x8*)&H2h[row * 40 + q * 8];
      al[mt] = *(const bf16x8*)&H2l[row * 40 + q * 8];
    }
#pragma unroll
    for (int nt = 0; nt < 8; ++nt) {
      int col = nt * 16 + nidx;
      bf16x8 bh = *(const bf16x8*)&Wth[col * 40 + q * 8];
      bf16x8 bl = *(const bf16x8*)&Wtl[col * 40 + q * 8];
#pragma unroll
      for (int mt = 0; mt < 2; ++mt) {
        acc[mt][nt] = __builtin_amdgcn_mfma_f32_16x16x32_bf16(
            ah[mt], bh, acc[mt][nt], 0, 0, 0);
        acc[mt][nt] = __builtin_amdgcn_mfma_f32_16x16x32_bf16(
            ah[mt], bl, acc[mt][nt], 0, 0, 0);
        acc[mt][nt] = __builtin_amdgcn_mfma_f32_16x16x32_bf16(
            al[mt], bh, acc[mt][nt], 0, 0, 0);
      }
    }
    __syncthreads();
  }

#pragma unroll
  for (int mt = 0; mt < 2; ++mt) {
    const int ebase = rowBase + w * 32 + mt * 16;
    const int pt0 = ebase >> 3;
#pragma unroll
    for (int nt = 0; nt < 8; ++nt) {
      f32x4 a = acc[mt][nt];
      float m = fmaxf(fmaxf(a[0], a[1]), fmaxf(a[2], a[3]));
      float o = fmaxf(m, __shfl_xor(m, 16, 64));
      int cg = colBase + nt * 16 + nidx;
      if (q == 0) {
        out[(size_t)pt0 * 256 + cg] = o + b4[cg];
      } else if (q == 2) {
        out[(size_t)(pt0 + 1) * 256 + cg] = o + b4[cg];
      }
    }
  }
}

extern "C" void kernel_launch(void* const* d_in, const int* in_sizes, int n_in,
                              void* d_out, int out_size, void* d_ws,
                              size_t ws_size, hipStream_t stream) {
  const float* pts = (const float*)d_in[0];
  const float* W1 = (const float*)d_in[1];
  const float* b1 = (const float*)d_in[2];
  const float* W2 = (const float*)d_in[3];
  const float* b2 = (const float*)d_in[4];
  const float* W3 = (const float*)d_in[5];
  const float* b3 = (const float*)d_in[6];
  const float* W4 = (const float*)d_in[7];
  const float* b4 = (const float*)d_in[8];
  float* out = (float*)d_out;

  // Workspace layout (floats), lifetime-overlapped:
  //   part_v [0, 4194304)          : vals->collect (region reused for AC)
  //   nbr    [4202496, +65536)     : collect->gemm1/gemm2
  //   y      [4268032, +1048576)   : gemm1->gemm_ac
  //   pts4   [5316608, +32768)     : pack->vals/collect (f4[8192])
  //   W4ht   [5349376, +16384)
  //   W4lt   [5365760, +16384)
  //   AC = part_v region [0, 2097152) (written after part_v is dead)
  float* w = (float*)d_ws;
  float* part_v = w;
  int* nbr = (int*)(w + 4202496);
  float* y = w + 4268032;
  float4* pts4 = (float4*)(w + 5316608);
  unsigned short* W4ht = (unsigned short*)(w + 5349376);
  unsigned short* W4lt = (unsigned short*)(w + 5365760);
  float* AC = w;

  // 1. KNN: pack pts4 -> slice top-8 values -> fused (extract-min thresh +
  //    masked collect + exact sort).
  pack_pts4_kernel<<<32, 256, 0, stream>>>(pts, pts4);
  knn_vals_kernel<<<dim3(32, NSLICE), 256, 0, stream>>>(pts4, part_v);
  knn_collect_kernel<<<2048, 256, 0, stream>>>(pts4, part_v, nbr);

  // 2. EdgeConv1 (fused H1 + GEMM + max8 + b2 + relu)
  gemm1_fused_kernel<<<dim3(2, 1024), 256, 0, stream>>>(pts, nbr, W1, b1, W2,
                                                        b2, y);

  // 3. EdgeConv2: AC = y@[W3|W3] (+b3), then MFMA H2+GEMM+max8+b4 -> out
  w4split_kernel<<<128, 256, 0, stream>>>(W4, W4ht, W4lt);
  gemm_ac_kernel<<<dim3(4, 128), 256, 0, stream>>>(y, W3, b3, AC);
  gemm2_mfma_kernel<<<dim3(2, 512), 256, 0, stream>>>(AC, nbr, W4ht, W4lt, b4,
                                                      out);
}

// Round 7
// 175.611 us; speedup vs baseline: 1.0631x; 1.0631x over previous
//
#include <hip/hip_runtime.h>

#define NPTS 8192
#define NSLICE 64
#define SLICE_LEN (NPTS / NSLICE)
#define KNN 8
#define SURV_CAP 32
#define TQ 32  // queries per thresh block

typedef short bf16x8 __attribute__((ext_vector_type(8)));
typedef float f32x4 __attribute__((ext_vector_type(4)));

// bf16 round-to-nearest-even split helpers.
__device__ __forceinline__ unsigned short f2bf(float x) {
  unsigned int u = __float_as_uint(x);
  return (unsigned short)((u + 0x7FFF + ((u >> 16) & 1)) >> 16);
}
__device__ __forceinline__ float bf2f(unsigned short s) {
  return __uint_as_float(((unsigned int)s) << 16);
}

// Distance helpers. contract(off) pins the value DAG (r3 failure lesson).
// vals and collect consume IDENTICAL pts4 inputs -> bit-identical distances;
// inflated thresholds (thresh kernel) add a second safety net.
__device__ __forceinline__ float dist_exact(float qx, float qy, float qz,
                                            float q2, float px, float py,
                                            float pz, float p2) {
#pragma clang fp contract(off)
  float dot = __fmaf_rn(qz, pz, __fmaf_rn(qy, py, __fmul_rn(qx, px)));
  float t1 = __fadd_rn(q2, p2);
  return __fadd_rn(t1, __fmul_rn(-2.0f, dot));
}

__device__ __forceinline__ float norm2_exact(float x, float y, float z) {
#pragma clang fp contract(off)
  return __fadd_rn(__fadd_rn(__fmul_rn(x, x), __fmul_rn(y, y)),
                   __fmul_rn(z, z));
}

__device__ __forceinline__ float med3(float a, float b, float c) {
  return __builtin_amdgcn_fmed3f(a, b, c);
}

// Monotone (d, idx) -> f64 key (used only in the tiny final sort).
__device__ __forceinline__ double pack_key(float d, int idx) {
  unsigned int ub = __float_as_uint(d);
  ub ^= (((unsigned int)((int)ub >> 31)) | 0x80000000u);
  unsigned int lo = (ub << 13) | (unsigned int)idx;
  unsigned int hi = 0x3ff00000u | (ub >> 19);
  return __hiloint2double((int)hi, (int)lo);
}

#define KEY_DECL                                                            \
  const double KINF = __longlong_as_double(0x7ff0000000000000LL);           \
  double k0 = KINF, k1 = KINF, k2 = KINF, k3 = KINF, k4 = KINF, k5 = KINF,  \
         k6 = KINF, k7 = KINF;
#define KB1(s)                                                              \
  {                                                                         \
    double mn = fmin(carry, k##s);                                          \
    carry = fmax(carry, k##s);                                              \
    k##s = mn;                                                              \
  }
#define KEY_INSERT(key)                                                     \
  {                                                                         \
    double carry = (key);                                                   \
    KB1(0) KB1(1) KB1(2) KB1(3) KB1(4) KB1(5) KB1(6) KB1(7)                 \
  }

// f32 value-only sorted-8 insert: 7 med3 + 1 min, in-place descending
// (each stage reads only not-yet-updated lower regs).
#define VINS(dv)                                                            \
  {                                                                         \
    float dd = (dv);                                                        \
    v7 = med3(dd, v6, v7);                                                  \
    v6 = med3(dd, v5, v6);                                                  \
    v5 = med3(dd, v4, v5);                                                  \
    v4 = med3(dd, v3, v4);                                                  \
    v3 = med3(dd, v2, v3);                                                  \
    v2 = med3(dd, v1, v2);                                                  \
    v1 = med3(dd, v0, v1);                                                  \
    v0 = fminf(dd, v0);                                                     \
  }

#define VDECL                                                               \
  const float FINF = __uint_as_float(0x7f800000u);                          \
  float v0 = FINF, v1 = FINF, v2 = FINF, v3 = FINF, v4 = FINF, v5 = FINF,   \
        v6 = FINF, v7 = FINF;

// ---------------------------------------------------------------------------
// Prep: W4 split (32768 ids) + pts4 pack (first 8192 ids). Both tiny and
// independent; fused to save one launch. pts4 = (x,y,z,norm2) is the SINGLE
// source of candidate/query bits for vals and collect.
// ---------------------------------------------------------------------------
__global__ __launch_bounds__(256) void prep_kernel(
    const float* __restrict__ W4, const float* __restrict__ pts,
    unsigned short* __restrict__ W4ht, unsigned short* __restrict__ W4lt,
    float4* __restrict__ pts4) {
  const int id = blockIdx.x * 256 + threadIdx.x;  // 32768
  const int k = id >> 8, c = id & 255;
  float v = W4[k * 256 + c];
  unsigned short hi = f2bf(v);
  unsigned short lo = f2bf(v - bf2f(hi));
  W4ht[c * 128 + k] = hi;
  W4lt[c * 128 + k] = lo;
  if (id < NPTS) {
    float x = pts[id * 3 + 0];
    float y = pts[id * 3 + 1];
    float z = pts[id * 3 + 2];
    pts4[id] = make_float4(x, y, z, norm2_exact(x, y, z));
  }
}

// ---------------------------------------------------------------------------
// KNN A: per (query, slice of 128) keep 8 smallest DISTANCE VALUES (f32).
// Slice staged in LDS (float4 copy from pts4 -- no math). Output transposed
// for coalescing: part_v[(slice*8+rank)*NPTS + q]; ranks ascending.
// ---------------------------------------------------------------------------
__global__ __launch_bounds__(256) void knn_vals_kernel(
    const float4* __restrict__ pts4, float* __restrict__ part_v) {
  __shared__ float4 sp[SLICE_LEN];
  const int t = threadIdx.x;
  const int q = blockIdx.x * 256 + t;
  const int jbase = blockIdx.y * SLICE_LEN;
  for (int p = t; p < SLICE_LEN; p += 256) sp[p] = pts4[jbase + p];
  __syncthreads();
  const float4 qp = pts4[q];
  const float qx = qp.x, qy = qp.y, qz = qp.z, q2 = qp.w;
  VDECL;
  for (int p = 0; p < SLICE_LEN; p += 8) {
    float4 c0 = sp[p + 0];
    float4 c1 = sp[p + 1];
    float4 c2 = sp[p + 2];
    float4 c3 = sp[p + 3];
    float4 c4 = sp[p + 4];
    float4 c5 = sp[p + 5];
    float4 c6 = sp[p + 6];
    float4 c7 = sp[p + 7];
    float d0 = dist_exact(qx, qy, qz, q2, c0.x, c0.y, c0.z, c0.w);
    float d1 = dist_exact(qx, qy, qz, q2, c1.x, c1.y, c1.z, c1.w);
    float d2 = dist_exact(qx, qy, qz, q2, c2.x, c2.y, c2.z, c2.w);
    float d3 = dist_exact(qx, qy, qz, q2, c3.x, c3.y, c3.z, c3.w);
    float d4 = dist_exact(qx, qy, qz, q2, c4.x, c4.y, c4.z, c4.w);
    float d5 = dist_exact(qx, qy, qz, q2, c5.x, c5.y, c5.z, c5.w);
    float d6 = dist_exact(qx, qy, qz, q2, c6.x, c6.y, c6.z, c6.w);
    float d7 = dist_exact(qx, qy, qz, q2, c7.x, c7.y, c7.z, c7.w);
    VINS(d0);
    VINS(d1);
    VINS(d2);
    VINS(d3);
    VINS(d4);
    VINS(d5);
    VINS(d6);
    VINS(d7);
  }
  float* o = &part_v[(size_t)(blockIdx.y * 8) * NPTS + q];
  o[0 * NPTS] = v0;
  o[1 * NPTS] = v1;
  o[2 * NPTS] = v2;
  o[3 * NPTS] = v3;
  o[4 * NPTS] = v4;
  o[5 * NPTS] = v5;
  o[6 * NPTS] = v6;
  o[7 * NPTS] = v7;
}

// ---------------------------------------------------------------------------
// KNN B (parallel merge): 8 threads/query. Each thread top-8-merges its 64
// values (8 slices x 8 ranks) -- exact, since any global-top-8 member is in
// its chunk's top-8 -- then thread c==0 merges the 8 sorted-8 lists and
// emits inflated thresholds: thr = v8*(1+4e-5) (collect gate), mask marks
// slices with slice-min <= v8*(1+8e-5). Collect gathers a tiny SUPERSET and
// final sort picks top-8 by collect-d keys (self-consistent selection).
// ---------------------------------------------------------------------------
__global__ __launch_bounds__(256) void knn_thresh_kernel(
    const float* __restrict__ part_v, float* __restrict__ thr,
    unsigned long long* __restrict__ mask) {
  __shared__ float v8s[TQ][8][9];   // [lq][chunk][rank] (pad 9: no conflicts)
  __shared__ float smin[TQ][65];    // slice mins (pad 65)
  const int t = threadIdx.x;
  const int lq = t >> 3, c = t & 7;
  const int q = blockIdx.x * TQ + lq;
  {
    VDECL;
#pragma unroll
    for (int s8 = 0; s8 < 8; ++s8) {
      const int s = c * 8 + s8;
      const float* col = &part_v[(size_t)(s * 8) * NPTS + q];
      float a0 = col[0 * (size_t)NPTS];
      float a1 = col[1 * (size_t)NPTS];
      float a2 = col[2 * (size_t)NPTS];
      float a3 = col[3 * (size_t)NPTS];
      float a4 = col[4 * (size_t)NPTS];
      float a5 = col[5 * (size_t)NPTS];
      float a6 = col[6 * (size_t)NPTS];
      float a7 = col[7 * (size_t)NPTS];
      smin[lq][s] = a0;  // rank-0 of a slice == slice min
      VINS(a0);
      VINS(a1);
      VINS(a2);
      VINS(a3);
      VINS(a4);
      VINS(a5);
      VINS(a6);
      VINS(a7);
    }
    v8s[lq][c][0] = v0;
    v8s[lq][c][1] = v1;
    v8s[lq][c][2] = v2;
    v8s[lq][c][3] = v3;
    v8s[lq][c][4] = v4;
    v8s[lq][c][5] = v5;
    v8s[lq][c][6] = v6;
    v8s[lq][c][7] = v7;
  }
  __syncthreads();
  if (c == 0) {
    VDECL;
#pragma unroll
    for (int s = 0; s < 8; ++s) {
      VINS(v8s[lq][s][0]);
      VINS(v8s[lq][s][1]);
      VINS(v8s[lq][s][2]);
      VINS(v8s[lq][s][3]);
      VINS(v8s[lq][s][4]);
      VINS(v8s[lq][s][5]);
      VINS(v8s[lq][s][6]);
      VINS(v8s[lq][s][7]);
    }
    const float tcol = v7 + fabsf(v7) * 4e-5f + 1e-20f;
    const float tmask = v7 + fabsf(v7) * 8e-5f + 2e-20f;
    unsigned long long mk = 0;
#pragma unroll
    for (int s = 0; s < NSLICE; ++s) {
      if (smin[lq][s] <= tmask) mk |= (1ull << s);
    }
    thr[q] = tcol;
    mask[q] = mk;
  }
}

// ---------------------------------------------------------------------------
// KNN C (fused collect+final): one WAVE per query. Scalar loop over the ~8
// marked slices; 64 lanes scan each 128-pt slice in 2 rounds (~1k candidates
// per query, not 8192). Survivors (d<=thr, ~8-10) go to an LDS keybuf via
// LDS atomics; lane 0 then sorts the exact f64 (d,idx) keys and writes nbr.
// Selection = 8 smallest (collect-d, idx) keys == jax.lax.top_k order.
// ---------------------------------------------------------------------------
__global__ __launch_bounds__(256) void knn_collect_kernel(
    const float4* __restrict__ pts4, const float* __restrict__ thr,
    const unsigned long long* __restrict__ mask, int* __restrict__ nbr) {
  __shared__ double keybuf[4][SURV_CAP];
  __shared__ int scnt[4];
  const int t = threadIdx.x;
  const int wv = t >> 6;
  const int lane = t & 63;
  const int q = blockIdx.x * 4 + wv;
  if (lane == 0) scnt[wv] = 0;
  __syncthreads();
  const float4 qp = pts4[q];
  const float qx = qp.x, qy = qp.y, qz = qp.z, q2 = qp.w;
  const float thrq = thr[q];
  unsigned long long m = mask[q];
  while (m) {
    const int s = (int)__ffsll(m) - 1;
    m &= m - 1;
    const int base = s * SLICE_LEN;
#pragma unroll
    for (int r = 0; r < SLICE_LEN / 64; ++r) {
      const int j = base + r * 64 + lane;
      const float4 cp = pts4[j];
      const float d = dist_exact(qx, qy, qz, q2, cp.x, cp.y, cp.z, cp.w);
      if (d <= thrq) {
        int slot = atomicAdd(&scnt[wv], 1);
        if (slot < SURV_CAP) keybuf[wv][slot] = pack_key(d, j);
      }
    }
  }
  __syncthreads();
  if (lane == 0) {
    int c = scnt[wv];
    if (c > SURV_CAP) c = SURV_CAP;
    KEY_DECL;
    for (int u = 0; u < c; ++u) {
      KEY_INSERT(keybuf[wv][u]);
    }
    int* o = &nbr[q * KNN];
    o[0] = __double2loint(k0) & 0x1fff;
    o[1] = __double2loint(k1) & 0x1fff;
    o[2] = __double2loint(k2) & 0x1fff;
    o[3] = __double2loint(k3) & 0x1fff;
    o[4] = __double2loint(k4) & 0x1fff;
    o[5] = __double2loint(k5) & 0x1fff;
    o[6] = __double2loint(k6) & 0x1fff;
    o[7] = __double2loint(k7) & 0x1fff;
  }
}

// ---------------------------------------------------------------------------
// Fused EdgeConv1: H1 tile in LDS, GEMM W2, max8, +b2, relu -> y (8192x128).
// ---------------------------------------------------------------------------
__global__ __launch_bounds__(256) void gemm1_fused_kernel(
    const float* __restrict__ pts, const int* __restrict__ nbr,
    const float* __restrict__ W1, const float* __restrict__ b1,
    const float* __restrict__ W2, const float* __restrict__ b2,
    float* __restrict__ y) {
  __shared__ float es[64][6];
  __shared__ float W1s[6][64];
  __shared__ float b1s[64];
  __shared__ float As[64][64];
  __shared__ float Bs[64][64];
  const int t = threadIdx.x;
  const int rowBase = blockIdx.y * 64;
  const int colBase = blockIdx.x * 64;

  for (int idx = t; idx < 384; idx += 256) W1s[idx >> 6][idx & 63] = W1[idx];
  if (t < 64) b1s[t] = b1[t];
  {
    int cq = t & 15, kr = t >> 4;
#pragma unroll
    for (int it = 0; it < 4; ++it) {
      int k = it * 16 + kr;
      *(float4*)&Bs[k][cq * 4] =
          *(const float4*)&W2[(size_t)k * 128 + colBase + cq * 4];
    }
  }
  if (t < 64) {
    int e = rowBase + t;
    int i = e >> 3;
    int j = nbr[e];
    float xi0 = pts[i * 3], xi1 = pts[i * 3 + 1], xi2 = pts[i * 3 + 2];
    es[t][0] = xi0;
    es[t][1] = xi1;
    es[t][2] = xi2;
    es[t][3] = pts[j * 3] - xi0;
    es[t][4] = pts[j * 3 + 1] - xi1;
    es[t][5] = pts[j * 3 + 2] - xi2;
  }
  __syncthreads();

  {
    const int e = t & 63, k0 = (t >> 6) * 16;
    const float f0 = es[e][0], f1 = es[e][1], f2 = es[e][2];
    const float f3 = es[e][3], f4 = es[e][4], f5 = es[e][5];
#pragma unroll
    for (int k = 0; k < 16; ++k) {
      int c = k0 + k;
      float v = b1s[c];
      v = fmaf(f0, W1s[0][c], v);
      v = fmaf(f1, W1s[1][c], v);
      v = fmaf(f2, W1s[2][c], v);
      v = fmaf(f3, W1s[3][c], v);
      v = fmaf(f4, W1s[4][c], v);
      v = fmaf(f5, W1s[5][c], v);
      As[c][e] = fmaxf(v, 0.0f);
    }
  }
  __syncthreads();

  const int tx = t & 15, ty = t >> 4;
  float acc[4][4] = {};
#pragma unroll 8
  for (int k = 0; k < 64; ++k) {
    float4 a = *(const float4*)&As[k][ty * 4];
    float4 b = *(const float4*)&Bs[k][tx * 4];
    const float ar[4] = {a.x, a.y, a.z, a.w};
    const float br[4] = {b.x, b.y, b.z, b.w};
#pragma unroll
    for (int i = 0; i < 4; ++i)
#pragma unroll
      for (int jj = 0; jj < 4; ++jj)
        acc[i][jj] = fmaf(ar[i], br[jj], acc[i][jj]);
  }
  __syncthreads();

  float* Mx = &As[0][0];
#pragma unroll
  for (int jj = 0; jj < 4; ++jj) {
    float m =
        fmaxf(fmaxf(acc[0][jj], acc[1][jj]), fmaxf(acc[2][jj], acc[3][jj]));
    Mx[ty * 64 + tx * 4 + jj] = m;
  }
  __syncthreads();
  if (t < 128) {
    int p = t >> 4, cq = t & 15;
    int c = cq * 4;
    float4 o;
    float* oa = (float*)&o;
#pragma unroll
    for (int jj = 0; jj < 4; ++jj) {
      float v = fmaxf(Mx[(2 * p) * 64 + c + jj], Mx[(2 * p + 1) * 64 + c + jj]);
      v += b2[colBase + c + jj];
      oa[jj] = fmaxf(v, 0.0f);
    }
    *(float4*)&y[(size_t)(blockIdx.y * 8 + p) * 128 + colBase + c] = o;
  }
}

// ---------------------------------------------------------------------------
// AC = y @ [W3top|W3bot] (+b3 on cols<128). 64x64 GEMM (8192x128x256).
// B staged DIRECTLY from W3 (col band lies in one half of the concat).
// ---------------------------------------------------------------------------
__global__ __launch_bounds__(256) void gemm_ac_kernel(
    const float* __restrict__ A, const float* __restrict__ W3,
    const float* __restrict__ bias, float* __restrict__ out) {
  __shared__ float As[64][64];
  __shared__ float Bs[64][64];
  const int t = threadIdx.x;
  const int tx = t & 15, ty = t >> 4;
  const int rowBase = blockIdx.y * 64;
  const int colBase = blockIdx.x * 64;
  const float4* A4 = (const float4*)A;
  float acc[4][4] = {};
  const int K = 128, Nglob = 256;

  for (int k0 = 0; k0 < K; k0 += 64) {
#pragma unroll
    for (int it = 0; it < 4; ++it) {
      int idx = it * 256 + t;
      int row = idx & 63, kq = idx >> 6;
      float4 av = A4[(size_t)(rowBase + row) * (K >> 2) + (k0 >> 2) + kq];
      As[kq * 4 + 0][row] = av.x;
      As[kq * 4 + 1][row] = av.y;
      As[kq * 4 + 2][row] = av.z;
      As[kq * 4 + 3][row] = av.w;
    }
#pragma unroll
    for (int it = 0; it < 4; ++it) {
      int idx = it * 256 + t;
      int cq = idx & 15, kr = idx >> 4;
      const float* src =
          (colBase < 128)
              ? &W3[(size_t)(k0 + kr) * 128 + colBase]
              : &W3[(size_t)(128 + k0 + kr) * 128 + (colBase - 128)];
      float4 bv = *(const float4*)&src[cq * 4];
      *(float4*)&Bs[kr][cq * 4] = bv;
    }
    __syncthreads();
#pragma unroll 8
    for (int k = 0; k < 64; ++k) {
      float4 a = *(const float4*)&As[k][ty * 4];
      float4 b = *(const float4*)&Bs[k][tx * 4];
      const float ar[4] = {a.x, a.y, a.z, a.w};
      const float br[4] = {b.x, b.y, b.z, b.w};
#pragma unroll
      for (int i = 0; i < 4; ++i)
#pragma unroll
        for (int jj = 0; jj < 4; ++jj)
          acc[i][jj] = fmaf(ar[i], br[jj], acc[i][jj]);
    }
    __syncthreads();
  }

#pragma unroll
  for (int i = 0; i < 4; ++i) {
    float4 o;
    float* oa = (float*)&o;
#pragma unroll
    for (int jj = 0; jj < 4; ++jj) {
      float v = acc[i][jj];
      int cg = colBase + tx * 4 + jj;
      if (cg < 128) v += bias[cg];
      oa[jj] = v;
    }
    *(float4*)&out[(size_t)(rowBase + ty * 4 + i) * Nglob + colBase + tx * 4] =
        o;
  }
}

// ---------------------------------------------------------------------------
// MFMA EdgeConv2 second layer (split-bf16), as R7 (verified):
// D = Hh*Wh + Hh*Wl + Hl*Wh in fp32 MFMA acc; in-register segmax + b4.
// ---------------------------------------------------------------------------
__global__ __launch_bounds__(256) void gemm2_mfma_kernel(
    const float* __restrict__ AC, const int* __restrict__ nbr,
    const unsigned short* __restrict__ W4ht,
    const unsigned short* __restrict__ W4lt, const float* __restrict__ b4,
    float* __restrict__ out) {
  __shared__ unsigned short H2h[128 * 40];
  __shared__ unsigned short H2l[128 * 40];
  __shared__ unsigned short Wth[128 * 40];
  __shared__ unsigned short Wtl[128 * 40];
  const int t = threadIdx.x;
  const int rowBase = blockIdx.y * 128;
  const int colBase = blockIdx.x * 128;
  const int eloc = t >> 1, hh = t & 1;
  const int kb = hh * 16;
  const int edge = rowBase + eloc;
  const int ip = edge >> 3;
  const int jp = nbr[edge];
  const float* ai_p = AC + (size_t)ip * 256;
  const float* ci_p = ai_p + 128;
  const float* cj_p = AC + (size_t)jp * 256 + 128;
  const int lane = t & 63;
  const int w = t >> 6;
  const int q = lane >> 4;
  const int nidx = lane & 15;

  f32x4 acc[2][8];
#pragma unroll
  for (int mt = 0; mt < 2; ++mt)
#pragma unroll
    for (int nt = 0; nt < 8; ++nt) acc[mt][nt] = (f32x4){0.f, 0.f, 0.f, 0.f};

  for (int p = 0; p < 4; ++p) {
    const int k0 = p * 32;
    {
      float h2[16];
      const float4* a4 = (const float4*)(ai_p + k0 + kb);
      const float4* c4 = (const float4*)(ci_p + k0 + kb);
      const float4* d4 = (const float4*)(cj_p + k0 + kb);
#pragma unroll
      for (int u = 0; u < 4; ++u) {
        float4 a = a4[u], c = c4[u], d = d4[u];
        h2[u * 4 + 0] = fmaxf(a.x + d.x - c.x, 0.f);
        h2[u * 4 + 1] = fmaxf(a.y + d.y - c.y, 0.f);
        h2[u * 4 + 2] = fmaxf(a.z + d.z - c.z, 0.f);
        h2[u * 4 + 3] = fmaxf(a.w + d.w - c.w, 0.f);
      }
      unsigned int hp[8], lp[8];
#pragma unroll
      for (int u = 0; u < 8; ++u) {
        unsigned short h0 = f2bf(h2[2 * u]), h1 = f2bf(h2[2 * u + 1]);
        hp[u] = (unsigned int)h0 | ((unsigned int)h1 << 16);
        unsigned short l0 = f2bf(h2[2 * u] - bf2f(h0));
        unsigned short l1 = f2bf(h2[2 * u + 1] - bf2f(h1));
        lp[u] = (unsigned int)l0 | ((unsigned int)l1 << 16);
      }
      *(uint4*)&H2h[eloc * 40 + kb] = make_uint4(hp[0], hp[1], hp[2], hp[3]);
      *(uint4*)&H2h[eloc * 40 + kb + 8] =
          make_uint4(hp[4], hp[5], hp[6], hp[7]);
      *(uint4*)&H2l[eloc * 40 + kb] = make_uint4(lp[0], lp[1], lp[2], lp[3]);
      *(uint4*)&H2l[eloc * 40 + kb + 8] =
          make_uint4(lp[4], lp[5], lp[6], lp[7]);
    }
    {
      const size_t src = (size_t)(colBase + eloc) * 128 + k0 + kb;
      *(uint4*)&Wth[eloc * 40 + kb] = *(const uint4*)&W4ht[src];
      *(uint4*)&Wth[eloc * 40 + kb + 8] = *(const uint4*)&W4ht[src + 8];
      *(uint4*)&Wtl[eloc * 40 + kb] = *(const uint4*)&W4lt[src];
      *(uint4*)&Wtl[eloc * 40 + kb + 8] = *(const uint4*)&W4lt[src + 8];
    }
    __syncthreads();
    bf16x8 ah[2], al[2];
#pragma unroll
    for (int mt = 0; mt < 2; ++mt) {
      int row = w * 32 + mt * 16 + nidx;
      ah[mt] = *(const bf16x8*)&H2h[row * 40 + q * 8];
      al[mt] = *(const bf16x8*)&H2l[row * 40 + q * 8];
    }
#pragma unroll
    for (int nt = 0; nt < 8; ++nt) {
      int col = nt * 16 + nidx;
      bf16x8 bh = *(const bf16x8*)&Wth[col * 40 + q * 8];
      bf16x8 bl = *(const bf16x8*)&Wtl[col * 40 + q * 8];
#pragma unroll
      for (int mt = 0; mt < 2; ++mt) {
        acc[mt][nt] = __builtin_amdgcn_mfma_f32_16x16x32_bf16(
            ah[mt], bh, acc[mt][nt], 0, 0, 0);
        acc[mt][nt] = __builtin_amdgcn_mfma_f32_16x16x32_bf16(
            ah[mt], bl, acc[mt][nt], 0, 0, 0);
        acc[mt][nt] = __builtin_amdgcn_mfma_f32_16x16x32_bf16(
            al[mt], bh, acc[mt][nt], 0, 0, 0);
      }
    }
    __syncthreads();
  }

#pragma unroll
  for (int mt = 0; mt < 2; ++mt) {
    const int ebase = rowBase + w * 32 + mt * 16;
    const int pt0 = ebase >> 3;
#pragma unroll
    for (int nt = 0; nt < 8; ++nt) {
      f32x4 a = acc[mt][nt];
      float m = fmaxf(fmaxf(a[0], a[1]), fmaxf(a[2], a[3]));
      float o = fmaxf(m, __shfl_xor(m, 16, 64));
      int cg = colBase + nt * 16 + nidx;
      if (q == 0) {
        out[(size_t)pt0 * 256 + cg] = o + b4[cg];
      } else if (q == 2) {
        out[(size_t)(pt0 + 1) * 256 + cg] = o + b4[cg];
      }
    }
  }
}

extern "C" void kernel_launch(void* const* d_in, const int* in_sizes, int n_in,
                              void* d_out, int out_size, void* d_ws,
                              size_t ws_size, hipStream_t stream) {
  const float* pts = (const float*)d_in[0];
  const float* W1 = (const float*)d_in[1];
  const float* b1 = (const float*)d_in[2];
  const float* W2 = (const float*)d_in[3];
  const float* b2 = (const float*)d_in[4];
  const float* W3 = (const float*)d_in[5];
  const float* b3 = (const float*)d_in[6];
  const float* W4 = (const float*)d_in[7];
  const float* b4 = (const float*)d_in[8];
  float* out = (float*)d_out;

  // Workspace layout (floats), lifetime-overlapped:
  //   part_v [0, 4194304)          : vals->thresh  (region reused for AC)
  //   thr    [4194304, +8192)      : thresh->collect
  //   nbr    [4202496, +65536)     : collect->gemm1/gemm2
  //   y      [4268032, +1048576)   : gemm1->gemm_ac
  //   mask   [5316608, +16384)     : thresh->collect (u64[8192])
  //   W4ht   [5332992, +16384)
  //   W4lt   [5349376, +16384)
  //   pts4   [5365760, +32768)     : prep->vals/collect (f4[8192])
  //   AC = part_v region [0, 2097152) (written after part_v is dead)
  float* w = (float*)d_ws;
  float* part_v = w;
  float* thr = w + 4194304;
  int* nbr = (int*)(w + 4202496);
  float* y = w + 4268032;
  unsigned long long* mask = (unsigned long long*)(w + 5316608);
  unsigned short* W4ht = (unsigned short*)(w + 5332992);
  unsigned short* W4lt = (unsigned short*)(w + 5349376);
  float4* pts4 = (float4*)(w + 5365760);
  float* AC = w;

  // 0. Prep: W4 bf16-split + pts4 pack (fused).
  prep_kernel<<<128, 256, 0, stream>>>(W4, pts, W4ht, W4lt, pts4);

  // 1. KNN: slice top-8 values -> parallel merge thresh -> masked collect.
  knn_vals_kernel<<<dim3(32, NSLICE), 256, 0, stream>>>(pts4, part_v);
  knn_thresh_kernel<<<NPTS / TQ, 256, 0, stream>>>(part_v, thr, mask);
  knn_collect_kernel<<<2048, 256, 0, stream>>>(pts4, thr, mask, nbr);

  // 2. EdgeConv1 (fused H1 + GEMM + max8 + b2 + relu)
  gemm1_fused_kernel<<<dim3(2, 1024), 256, 0, stream>>>(pts, nbr, W1, b1, W2,
                                                        b2, y);

  // 3. EdgeConv2: AC = y@[W3|W3] (+b3), then MFMA H2+GEMM+max8+b4 -> out
  gemm_ac_kernel<<<dim3(4, 128), 256, 0, stream>>>(y, W3, b3, AC);
  gemm2_mfma_kernel<<<dim3(2, 512), 256, 0, stream>>>(AC, nbr, W4ht, W4lt, b4,
                                                      out);
}

// Round 8
// 161.750 us; speedup vs baseline: 1.1542x; 1.0857x over previous
//
#include <hip/hip_runtime.h>

#define NPTS 8192
#define NSLICE 64
#define SLICE_LEN (NPTS / NSLICE)
#define KNN 8
#define SURV_CAP 48
#define TQ 32  // queries per thresh block

typedef short bf16x8 __attribute__((ext_vector_type(8)));
typedef float f32x4 __attribute__((ext_vector_type(4)));

// bf16 round-to-nearest-even split helpers.
__device__ __forceinline__ unsigned short f2bf(float x) {
  unsigned int u = __float_as_uint(x);
  return (unsigned short)((u + 0x7FFF + ((u >> 16) & 1)) >> 16);
}
__device__ __forceinline__ float bf2f(unsigned short s) {
  return __uint_as_float(((unsigned int)s) << 16);
}

// Distance helpers. contract(off) pins the value DAG (r3 failure lesson).
// vals and collect consume IDENTICAL pts4 inputs -> bit-identical distances;
// inflated thresholds (thresh kernel) add a second safety net.
__device__ __forceinline__ float dist_exact(float qx, float qy, float qz,
                                            float q2, float px, float py,
                                            float pz, float p2) {
#pragma clang fp contract(off)
  float dot = __fmaf_rn(qz, pz, __fmaf_rn(qy, py, __fmul_rn(qx, px)));
  float t1 = __fadd_rn(q2, p2);
  return __fadd_rn(t1, __fmul_rn(-2.0f, dot));
}

__device__ __forceinline__ float norm2_exact(float x, float y, float z) {
#pragma clang fp contract(off)
  return __fadd_rn(__fadd_rn(__fmul_rn(x, x), __fmul_rn(y, y)),
                   __fmul_rn(z, z));
}

__device__ __forceinline__ float med3(float a, float b, float c) {
  return __builtin_amdgcn_fmed3f(a, b, c);
}

// Monotone (d, idx) -> f64 key (used only in the tiny final sort).
__device__ __forceinline__ double pack_key(float d, int idx) {
  unsigned int ub = __float_as_uint(d);
  ub ^= (((unsigned int)((int)ub >> 31)) | 0x80000000u);
  unsigned int lo = (ub << 13) | (unsigned int)idx;
  unsigned int hi = 0x3ff00000u | (ub >> 19);
  return __hiloint2double((int)hi, (int)lo);
}

#define KEY_DECL                                                            \
  const double KINF = __longlong_as_double(0x7ff0000000000000LL);           \
  double k0 = KINF, k1 = KINF, k2 = KINF, k3 = KINF, k4 = KINF, k5 = KINF,  \
         k6 = KINF, k7 = KINF;
#define KB1(s)                                                              \
  {                                                                         \
    double mn = fmin(carry, k##s);                                          \
    carry = fmax(carry, k##s);                                              \
    k##s = mn;                                                              \
  }
#define KEY_INSERT(key)                                                     \
  {                                                                         \
    double carry = (key);                                                   \
    KB1(0) KB1(1) KB1(2) KB1(3) KB1(4) KB1(5) KB1(6) KB1(7)                 \
  }

// f32 value-only sorted-8 insert: 7 med3 + 1 min, in-place descending
// (each stage reads only not-yet-updated lower regs).
#define VINS(dv)                                                            \
  {                                                                         \
    float dd = (dv);                                                        \
    v7 = med3(dd, v6, v7);                                                  \
    v6 = med3(dd, v5, v6);                                                  \
    v5 = med3(dd, v4, v5);                                                  \
    v4 = med3(dd, v3, v4);                                                  \
    v3 = med3(dd, v2, v2 < dd ? dd : v3);                                   \
    v2 = med3(dd, v1, v2);                                                  \
    v1 = med3(dd, v0, v1);                                                  \
    v0 = fminf(dd, v0);                                                     \
  }

// NOTE: the line above for v3 must be the plain med3 form; fixed below.
#undef VINS
#define VINS(dv)                                                            \
  {                                                                         \
    float dd = (dv);                                                        \
    v7 = med3(dd, v6, v7);                                                  \
    v6 = med3(dd, v5, v6);                                                  \
    v5 = med3(dd, v4, v5);                                                  \
    v4 = med3(dd, v3, v4);                                                  \
    v3 = med3(dd, v2, v3);                                                  \
    v2 = med3(dd, v1, v2);                                                  \
    v1 = med3(dd, v0, v1);                                                  \
    v0 = fminf(dd, v0);                                                     \
  }

#define VDECL                                                               \
  const float FINF = __uint_as_float(0x7f800000u);                          \
  float v0 = FINF, v1 = FINF, v2 = FINF, v3 = FINF, v4 = FINF, v5 = FINF,   \
        v6 = FINF, v7 = FINF;

// f32 value-only sorted-2 insert (slice-local): 2 ops.
#define VINS2(dv)                                                           \
  {                                                                         \
    float dd = (dv);                                                        \
    s1 = med3(dd, s0, s1);                                                  \
    s0 = fminf(dd, s0);                                                     \
  }

// ---------------------------------------------------------------------------
// Prep: W4 split (32768 ids) + pts4 pack (first 8192 ids). Both tiny and
// independent; fused to save one launch. pts4 = (x,y,z,norm2) is the SINGLE
// source of candidate/query bits for vals and collect.
// ---------------------------------------------------------------------------
__global__ __launch_bounds__(256) void prep_kernel(
    const float* __restrict__ W4, const float* __restrict__ pts,
    unsigned short* __restrict__ W4ht, unsigned short* __restrict__ W4lt,
    float4* __restrict__ pts4) {
  const int id = blockIdx.x * 256 + threadIdx.x;  // 32768
  const int k = id >> 8, c = id & 255;
  float v = W4[k * 256 + c];
  unsigned short hi = f2bf(v);
  unsigned short lo = f2bf(v - bf2f(hi));
  W4ht[c * 128 + k] = hi;
  W4lt[c * 128 + k] = lo;
  if (id < NPTS) {
    float x = pts[id * 3 + 0];
    float y = pts[id * 3 + 1];
    float z = pts[id * 3 + 2];
    pts4[id] = make_float4(x, y, z, norm2_exact(x, y, z));
  }
}

// ---------------------------------------------------------------------------
// KNN A: per (query, slice of 128) keep the 2 smallest DISTANCE VALUES.
// Top-2 (not top-8) suffices: thresh only needs (a) per-slice mins for the
// mask and (b) a pool of genuine distances whose 8th-smallest upper-bounds
// the true v8 (any 8 distinct genuine distances do). 8 VALU ops/pair
// instead of 14. Output: part_v[(slice*2+rank)*NPTS + q], ranks ascending.
// ---------------------------------------------------------------------------
__global__ __launch_bounds__(256) void knn_vals_kernel(
    const float4* __restrict__ pts4, float* __restrict__ part_v) {
  __shared__ float4 sp[SLICE_LEN];
  const int t = threadIdx.x;
  const int q = blockIdx.x * 256 + t;
  const int jbase = blockIdx.y * SLICE_LEN;
  for (int p = t; p < SLICE_LEN; p += 256) sp[p] = pts4[jbase + p];
  __syncthreads();
  const float4 qp = pts4[q];
  const float qx = qp.x, qy = qp.y, qz = qp.z, q2 = qp.w;
  const float FINF = __uint_as_float(0x7f800000u);
  float s0 = FINF, s1 = FINF;
  for (int p = 0; p < SLICE_LEN; p += 8) {
    float4 c0 = sp[p + 0];
    float4 c1 = sp[p + 1];
    float4 c2 = sp[p + 2];
    float4 c3 = sp[p + 3];
    float4 c4 = sp[p + 4];
    float4 c5 = sp[p + 5];
    float4 c6 = sp[p + 6];
    float4 c7 = sp[p + 7];
    float d0 = dist_exact(qx, qy, qz, q2, c0.x, c0.y, c0.z, c0.w);
    float d1 = dist_exact(qx, qy, qz, q2, c1.x, c1.y, c1.z, c1.w);
    float d2 = dist_exact(qx, qy, qz, q2, c2.x, c2.y, c2.z, c2.w);
    float d3 = dist_exact(qx, qy, qz, q2, c3.x, c3.y, c3.z, c3.w);
    float d4 = dist_exact(qx, qy, qz, q2, c4.x, c4.y, c4.z, c4.w);
    float d5 = dist_exact(qx, qy, qz, q2, c5.x, c5.y, c5.z, c5.w);
    float d6 = dist_exact(qx, qy, qz, q2, c6.x, c6.y, c6.z, c6.w);
    float d7 = dist_exact(qx, qy, qz, q2, c7.x, c7.y, c7.z, c7.w);
    VINS2(d0);
    VINS2(d1);
    VINS2(d2);
    VINS2(d3);
    VINS2(d4);
    VINS2(d5);
    VINS2(d6);
    VINS2(d7);
  }
  float* o = &part_v[(size_t)(blockIdx.y * 2) * NPTS + q];
  o[0 * NPTS] = s0;
  o[1 * NPTS] = s1;
}

// ---------------------------------------------------------------------------
// KNN B (parallel merge): 8 threads/query over the 128-value pool (64 slices
// x top-2). Each thread top-8-merges its 16 values (exact: any pool-top-8
// member is within its chunk's top-8); thread c==0 merges the 8 sorted-8
// lists -> tau = 8th-smallest of the pool >= true v8 (8 distinct genuine
// distances always upper-bound the global 8th). Inflated thresholds:
// thr = tau*(1+4e-5) (collect gate), mask marks slice-min <= tau*(1+8e-5).
// Collect gathers a small SUPERSET (~10-14) and the final key-sort picks the
// true top-8 (self-consistent selection == jax.lax.top_k order).
// ---------------------------------------------------------------------------
__global__ __launch_bounds__(256) void knn_thresh_kernel(
    const float* __restrict__ part_v, float* __restrict__ thr,
    unsigned long long* __restrict__ mask) {
  __shared__ float v8s[TQ][8][9];   // [lq][chunk][rank] (pad 9: no conflicts)
  __shared__ float smin[TQ][65];    // slice mins (pad 65)
  const int t = threadIdx.x;
  const int lq = t >> 3, c = t & 7;
  const int q = blockIdx.x * TQ + lq;
  {
    VDECL;
#pragma unroll
    for (int s8 = 0; s8 < 8; ++s8) {
      const int s = c * 8 + s8;
      const float* col = &part_v[(size_t)(s * 2) * NPTS + q];
      float a0 = col[0 * (size_t)NPTS];
      float a1 = col[1 * (size_t)NPTS];
      smin[lq][s] = a0;  // rank-0 of a slice == slice min
      VINS(a0);
      VINS(a1);
    }
    v8s[lq][c][0] = v0;
    v8s[lq][c][1] = v1;
    v8s[lq][c][2] = v2;
    v8s[lq][c][3] = v3;
    v8s[lq][c][4] = v4;
    v8s[lq][c][5] = v5;
    v8s[lq][c][6] = v6;
    v8s[lq][c][7] = v7;
  }
  __syncthreads();
  if (c == 0) {
    VDECL;
#pragma unroll
    for (int s = 0; s < 8; ++s) {
      VINS(v8s[lq][s][0]);
      VINS(v8s[lq][s][1]);
      VINS(v8s[lq][s][2]);
      VINS(v8s[lq][s][3]);
      VINS(v8s[lq][s][4]);
      VINS(v8s[lq][s][5]);
      VINS(v8s[lq][s][6]);
      VINS(v8s[lq][s][7]);
    }
    const float tcol = v7 + fabsf(v7) * 4e-5f + 1e-20f;
    const float tmask = v7 + fabsf(v7) * 8e-5f + 2e-20f;
    unsigned long long mk = 0;
#pragma unroll
    for (int s = 0; s < NSLICE; ++s) {
      if (smin[lq][s] <= tmask) mk |= (1ull << s);
    }
    thr[q] = tcol;
    mask[q] = mk;
  }
}

// ---------------------------------------------------------------------------
// KNN C (fused collect+final): one WAVE per query. Scalar loop over the ~8
// marked slices; 64 lanes scan each 128-pt slice in 2 rounds (~1k candidates
// per query, not 8192). Survivors (d<=thr, ~10-14) go to an LDS keybuf via
// LDS atomics; lane 0 then sorts the exact f64 (d,idx) keys and writes nbr.
// Selection = 8 smallest (collect-d, idx) keys == jax.lax.top_k order.
// ---------------------------------------------------------------------------
__global__ __launch_bounds__(256) void knn_collect_kernel(
    const float4* __restrict__ pts4, const float* __restrict__ thr,
    const unsigned long long* __restrict__ mask, int* __restrict__ nbr) {
  __shared__ double keybuf[4][SURV_CAP];
  __shared__ int scnt[4];
  const int t = threadIdx.x;
  const int wv = t >> 6;
  const int lane = t & 63;
  const int q = blockIdx.x * 4 + wv;
  if (lane == 0) scnt[wv] = 0;
  __syncthreads();
  const float4 qp = pts4[q];
  const float qx = qp.x, qy = qp.y, qz = qp.z, q2 = qp.w;
  const float thrq = thr[q];
  unsigned long long m = mask[q];
  while (m) {
    const int s = (int)__ffsll(m) - 1;
    m &= m - 1;
    const int base = s * SLICE_LEN;
#pragma unroll
    for (int r = 0; r < SLICE_LEN / 64; ++r) {
      const int j = base + r * 64 + lane;
      const float4 cp = pts4[j];
      const float d = dist_exact(qx, qy, qz, q2, cp.x, cp.y, cp.z, cp.w);
      if (d <= thrq) {
        int slot = atomicAdd(&scnt[wv], 1);
        if (slot < SURV_CAP) keybuf[wv][slot] = pack_key(d, j);
      }
    }
  }
  __syncthreads();
  if (lane == 0) {
    int c = scnt[wv];
    if (c > SURV_CAP) c = SURV_CAP;
    KEY_DECL;
    for (int u = 0; u < c; ++u) {
      KEY_INSERT(keybuf[wv][u]);
    }
    int* o = &nbr[q * KNN];
    o[0] = __double2loint(k0) & 0x1fff;
    o[1] = __double2loint(k1) & 0x1fff;
    o[2] = __double2loint(k2) & 0x1fff;
    o[3] = __double2loint(k3) & 0x1fff;
    o[4] = __double2loint(k4) & 0x1fff;
    o[5] = __double2loint(k5) & 0x1fff;
    o[6] = __double2loint(k6) & 0x1fff;
    o[7] = __double2loint(k7) & 0x1fff;
  }
}

// ---------------------------------------------------------------------------
// Fused EdgeConv1: H1 tile in LDS, GEMM W2, max8, +b2, relu -> y (8192x128).
// ---------------------------------------------------------------------------
__global__ __launch_bounds__(256) void gemm1_fused_kernel(
    const float* __restrict__ pts, const int* __restrict__ nbr,
    const float* __restrict__ W1, const float* __restrict__ b1,
    const float* __restrict__ W2, const float* __restrict__ b2,
    float* __restrict__ y) {
  __shared__ float es[64][6];
  __shared__ float W1s[6][64];
  __shared__ float b1s[64];
  __shared__ float As[64][64];
  __shared__ float Bs[64][64];
  const int t = threadIdx.x;
  const int rowBase = blockIdx.y * 64;
  const int colBase = blockIdx.x * 64;

  for (int idx = t; idx < 384; idx += 256) W1s[idx >> 6][idx & 63] = W1[idx];
  if (t < 64) b1s[t] = b1[t];
  {
    int cq = t & 15, kr = t >> 4;
#pragma unroll
    for (int it = 0; it < 4; ++it) {
      int k = it * 16 + kr;
      *(float4*)&Bs[k][cq * 4] =
          *(const float4*)&W2[(size_t)k * 128 + colBase + cq * 4];
    }
  }
  if (t < 64) {
    int e = rowBase + t;
    int i = e >> 3;
    int j = nbr[e];
    float xi0 = pts[i * 3], xi1 = pts[i * 3 + 1], xi2 = pts[i * 3 + 2];
    es[t][0] = xi0;
    es[t][1] = xi1;
    es[t][2] = xi2;
    es[t][3] = pts[j * 3] - xi0;
    es[t][4] = pts[j * 3 + 1] - xi1;
    es[t][5] = pts[j * 3 + 2] - xi2;
  }
  __syncthreads();

  {
    const int e = t & 63, k0 = (t >> 6) * 16;
    const float f0 = es[e][0], f1 = es[e][1], f2 = es[e][2];
    const float f3 = es[e][3], f4 = es[e][4], f5 = es[e][5];
#pragma unroll
    for (int k = 0; k < 16; ++k) {
      int c = k0 + k;
      float v = b1s[c];
      v = fmaf(f0, W1s[0][c], v);
      v = fmaf(f1, W1s[1][c], v);
      v = fmaf(f2, W1s[2][c], v);
      v = fmaf(f3, W1s[3][c], v);
      v = fmaf(f4, W1s[4][c], v);
      v = fmaf(f5, W1s[5][c], v);
      As[c][e] = fmaxf(v, 0.0f);
    }
  }
  __syncthreads();

  const int tx = t & 15, ty = t >> 4;
  float acc[4][4] = {};
#pragma unroll 8
  for (int k = 0; k < 64; ++k) {
    float4 a = *(const float4*)&As[k][ty * 4];
    float4 b = *(const float4*)&Bs[k][tx * 4];
    const float ar[4] = {a.x, a.y, a.z, a.w};
    const float br[4] = {b.x, b.y, b.z, b.w};
#pragma unroll
    for (int i = 0; i < 4; ++i)
#pragma unroll
      for (int jj = 0; jj < 4; ++jj)
        acc[i][jj] = fmaf(ar[i], br[jj], acc[i][jj]);
  }
  __syncthreads();

  float* Mx = &As[0][0];
#pragma unroll
  for (int jj = 0; jj < 4; ++jj) {
    float m =
        fmaxf(fmaxf(acc[0][jj], acc[1][jj]), fmaxf(acc[2][jj], acc[3][jj]));
    Mx[ty * 64 + tx * 4 + jj] = m;
  }
  __syncthreads();
  if (t < 128) {
    int p = t >> 4, cq = t & 15;
    int c = cq * 4;
    float4 o;
    float* oa = (float*)&o;
#pragma unroll
    for (int jj = 0; jj < 4; ++jj) {
      float v = fmaxf(Mx[(2 * p) * 64 + c + jj], Mx[(2 * p + 1) * 64 + c + jj]);
      v += b2[colBase + c + jj];
      oa[jj] = fmaxf(v, 0.0f);
    }
    *(float4*)&y[(size_t)(blockIdx.y * 8 + p) * 128 + colBase + c] = o;
  }
}

// ---------------------------------------------------------------------------
// AC = y @ [W3top|W3bot] (+b3 on cols<128). 64x64 GEMM (8192x128x256).
// B staged DIRECTLY from W3 (col band lies in one half of the concat).
// ---------------------------------------------------------------------------
__global__ __launch_bounds__(256) void gemm_ac_kernel(
    const float* __restrict__ A, const float* __restrict__ W3,
    const float* __restrict__ bias, float* __restrict__ out) {
  __shared__ float As[64][64];
  __shared__ float Bs[64][64];
  const int t = threadIdx.x;
  const int tx = t & 15, ty = t >> 4;
  const int rowBase = blockIdx.y * 64;
  const int colBase = blockIdx.x * 64;
  const float4* A4 = (const float4*)A;
  float acc[4][4] = {};
  const int K = 128, Nglob = 256;

  for (int k0 = 0; k0 < K; k0 += 64) {
#pragma unroll
    for (int it = 0; it < 4; ++it) {
      int idx = it * 256 + t;
      int row = idx & 63, kq = idx >> 6;
      float4 av = A4[(size_t)(rowBase + row) * (K >> 2) + (k0 >> 2) + kq];
      As[kq * 4 + 0][row] = av.x;
      As[kq * 4 + 1][row] = av.y;
      As[kq * 4 + 2][row] = av.z;
      As[kq * 4 + 3][row] = av.w;
    }
#pragma unroll
    for (int it = 0; it < 4; ++it) {
      int idx = it * 256 + t;
      int cq = idx & 15, kr = idx >> 4;
      const float* src =
          (colBase < 128)
              ? &W3[(size_t)(k0 + kr) * 128 + colBase]
              : &W3[(size_t)(128 + k0 + kr) * 128 + (colBase - 128)];
      float4 bv = *(const float4*)&src[cq * 4];
      *(float4*)&Bs[kr][cq * 4] = bv;
    }
    __syncthreads();
#pragma unroll 8
    for (int k = 0; k < 64; ++k) {
      float4 a = *(const float4*)&As[k][ty * 4];
      float4 b = *(const float4*)&Bs[k][tx * 4];
      const float ar[4] = {a.x, a.y, a.z, a.w};
      const float br[4] = {b.x, b.y, b.z, b.w};
#pragma unroll
      for (int i = 0; i < 4; ++i)
#pragma unroll
        for (int jj = 0; jj < 4; ++jj)
          acc[i][jj] = fmaf(ar[i], br[jj], acc[i][jj]);
    }
    __syncthreads();
  }

#pragma unroll
  for (int i = 0; i < 4; ++i) {
    float4 o;
    float* oa = (float*)&o;
#pragma unroll
    for (int jj = 0; jj < 4; ++jj) {
      float v = acc[i][jj];
      int cg = colBase + tx * 4 + jj;
      if (cg < 128) v += bias[cg];
      oa[jj] = v;
    }
    *(float4*)&out[(size_t)(rowBase + ty * 4 + i) * Nglob + colBase + tx * 4] =
        o;
  }
}

// ---------------------------------------------------------------------------
// MFMA EdgeConv2 second layer (split-bf16), as R7 (verified):
// D = Hh*Wh + Hh*Wl + Hl*Wh in fp32 MFMA acc; in-register segmax + b4.
// ---------------------------------------------------------------------------
__global__ __launch_bounds__(256) void gemm2_mfma_kernel(
    const float* __restrict__ AC, const int* __restrict__ nbr,
    const unsigned short* __restrict__ W4ht,
    const unsigned short* __restrict__ W4lt, const float* __restrict__ b4,
    float* __restrict__ out) {
  __shared__ unsigned short H2h[128 * 40];
  __shared__ unsigned short H2l[128 * 40];
  __shared__ unsigned short Wth[128 * 40];
  __shared__ unsigned short Wtl[128 * 40];
  const int t = threadIdx.x;
  const int rowBase = blockIdx.y * 128;
  const int colBase = blockIdx.x * 128;
  const int eloc = t >> 1, hh = t & 1;
  const int kb = hh * 16;
  const int edge = rowBase + eloc;
  const int ip = edge >> 3;
  const int jp = nbr[edge];
  const float* ai_p = AC + (size_t)ip * 256;
  const float* ci_p = ai_p + 128;
  const float* cj_p = AC + (size_t)jp * 256 + 128;
  const int lane = t & 63;
  const int w = t >> 6;
  const int q = lane >> 4;
  const int nidx = lane & 15;

  f32x4 acc[2][8];
#pragma unroll
  for (int mt = 0; mt < 2; ++mt)
#pragma unroll
    for (int nt = 0; nt < 8; ++nt) acc[mt][nt] = (f32x4){0.f, 0.f, 0.f, 0.f};

  for (int p = 0; p < 4; ++p) {
    const int k0 = p * 32;
    {
      float h2[16];
      const float4* a4 = (const float4*)(ai_p + k0 + kb);
      const float4* c4 = (const float4*)(ci_p + k0 + kb);
      const float4* d4 = (const float4*)(cj_p + k0 + kb);
#pragma unroll
      for (int u = 0; u < 4; ++u) {
        float4 a = a4[u], c = c4[u], d = d4[u];
        h2[u * 4 + 0] = fmaxf(a.x + d.x - c.x, 0.f);
        h2[u * 4 + 1] = fmaxf(a.y + d.y - c.y, 0.f);
        h2[u * 4 + 2] = fmaxf(a.z + d.z - c.z, 0.f);
        h2[u * 4 + 3] = fmaxf(a.w + d.w - c.w, 0.f);
      }
      unsigned int hp[8], lp[8];
#pragma unroll
      for (int u = 0; u < 8; ++u) {
        unsigned short h0 = f2bf(h2[2 * u]), h1 = f2bf(h2[2 * u + 1]);
        hp[u] = (unsigned int)h0 | ((unsigned int)h1 << 16);
        unsigned short l0 = f2bf(h2[2 * u] - bf2f(h0));
        unsigned short l1 = f2bf(h2[2 * u + 1] - bf2f(h1));
        lp[u] = (unsigned int)l0 | ((unsigned int)l1 << 16);
      }
      *(uint4*)&H2h[eloc * 40 + kb] = make_uint4(hp[0], hp[1], hp[2], hp[3]);
      *(uint4*)&H2h[eloc * 40 + kb + 8] =
          make_uint4(hp[4], hp[5], hp[6], hp[7]);
      *(uint4*)&H2l[eloc * 40 + kb] = make_uint4(lp[0], lp[1], lp[2], lp[3]);
      *(uint4*)&H2l[eloc * 40 + kb + 8] =
          make_uint4(lp[4], lp[5], lp[6], lp[7]);
    }
    {
      const size_t src = (size_t)(colBase + eloc) * 128 + k0 + kb;
      *(uint4*)&Wth[eloc * 40 + kb] = *(const uint4*)&W4ht[src];
      *(uint4*)&Wth[eloc * 40 + kb + 8] = *(const uint4*)&W4ht[src + 8];
      *(uint4*)&Wtl[eloc * 40 + kb] = *(const uint4*)&W4lt[src];
      *(uint4*)&Wtl[eloc * 40 + kb + 8] = *(const uint4*)&W4lt[src + 8];
    }
    __syncthreads();
    bf16x8 ah[2], al[2];
#pragma unroll
    for (int mt = 0; mt < 2; ++mt) {
      int row = w * 32 + mt * 16 + nidx;
      ah[mt] = *(const bf16x8*)&H2h[row * 40 + q * 8];
      al[mt] = *(const bf16x8*)&H2l[row * 40 + q * 8];
    }
#pragma unroll
    for (int nt = 0; nt < 8; ++nt) {
      int col = nt * 16 + nidx;
      bf16x8 bh = *(const bf16x8*)&Wth[col * 40 + q * 8];
      bf16x8 bl = *(const bf16x8*)&Wtl[col * 40 + q * 8];
#pragma unroll
      for (int mt = 0; mt < 2; ++mt) {
        acc[mt][nt] = __builtin_amdgcn_mfma_f32_16x16x32_bf16(
            ah[mt], bh, acc[mt][nt], 0, 0, 0);
        acc[mt][nt] = __builtin_amdgcn_mfma_f32_16x16x32_bf16(
            ah[mt], bl, acc[mt][nt], 0, 0, 0);
        acc[mt][nt] = __builtin_amdgcn_mfma_f32_16x16x32_bf16(
            al[mt], bh, acc[mt][nt], 0, 0, 0);
      }
    }
    __syncthreads();
  }

#pragma unroll
  for (int mt = 0; mt < 2; ++mt) {
    const int ebase = rowBase + w * 32 + mt * 16;
    const int pt0 = ebase >> 3;
#pragma unroll
    for (int nt = 0; nt < 8; ++nt) {
      f32x4 a = acc[mt][nt];
      float m = fmaxf(fmaxf(a[0], a[1]), fmaxf(a[2], a[3]));
      float o = fmaxf(m, __shfl_xor(m, 16, 64));
      int cg = colBase + nt * 16 + nidx;
      if (q == 0) {
        out[(size_t)pt0 * 256 + cg] = o + b4[cg];
      } else if (q == 2) {
        out[(size_t)(pt0 + 1) * 256 + cg] = o + b4[cg];
      }
    }
  }
}

extern "C" void kernel_launch(void* const* d_in, const int* in_sizes, int n_in,
                              void* d_out, int out_size, void* d_ws,
                              size_t ws_size, hipStream_t stream) {
  const float* pts = (const float*)d_in[0];
  const float* W1 = (const float*)d_in[1];
  const float* b1 = (const float*)d_in[2];
  const float* W2 = (const float*)d_in[3];
  const float* b2 = (const float*)d_in[4];
  const float* W3 = (const float*)d_in[5];
  const float* b3 = (const float*)d_in[6];
  const float* W4 = (const float*)d_in[7];
  const float* b4 = (const float*)d_in[8];
  float* out = (float*)d_out;

  // Workspace layout (floats), lifetime-overlapped:
  //   part_v [0, 1048576)          : vals->thresh (within AC region, dead
  //                                  before gemm_ac writes AC)
  //   thr    [4194304, +8192)      : thresh->collect
  //   nbr    [4202496, +65536)     : collect->gemm1/gemm2
  //   y      [4268032, +1048576)   : gemm1->gemm_ac
  //   mask   [5316608, +16384)     : thresh->collect (u64[8192])
  //   W4ht   [5332992, +16384)
  //   W4lt   [5349376, +16384)
  //   pts4   [5365760, +32768)     : prep->vals/collect (f4[8192])
  //   AC = [0, 2097152) (written after part_v is dead)
  float* w = (float*)d_ws;
  float* part_v = w;
  float* thr = w + 4194304;
  int* nbr = (int*)(w + 4202496);
  float* y = w + 4268032;
  unsigned long long* mask = (unsigned long long*)(w + 5316608);
  unsigned short* W4ht = (unsigned short*)(w + 5332992);
  unsigned short* W4lt = (unsigned short*)(w + 5349376);
  float4* pts4 = (float4*)(w + 5365760);
  float* AC = w;

  // 0. Prep: W4 bf16-split + pts4 pack (fused).
  prep_kernel<<<128, 256, 0, stream>>>(W4, pts, W4ht, W4lt, pts4);

  // 1. KNN: slice top-2 values -> parallel pool-merge thresh -> collect.
  knn_vals_kernel<<<dim3(32, NSLICE), 256, 0, stream>>>(pts4, part_v);
  knn_thresh_kernel<<<NPTS / TQ, 256, 0, stream>>>(part_v, thr, mask);
  knn_collect_kernel<<<2048, 256, 0, stream>>>(pts4, thr, mask, nbr);

  // 2. EdgeConv1 (fused H1 + GEMM + max8 + b2 + relu)
  gemm1_fused_kernel<<<dim3(2, 1024), 256, 0, stream>>>(pts, nbr, W1, b1, W2,
                                                        b2, y);

  // 3. EdgeConv2: AC = y@[W3|W3] (+b3), then MFMA H2+GEMM+max8+b4 -> out
  gemm_ac_kernel<<<dim3(4, 128), 256, 0, stream>>>(y, W3, b3, AC);
  gemm2_mfma_kernel<<<dim3(2, 512), 256, 0, stream>>>(AC, nbr, W4ht, W4lt, b4,
                                                      out);
}

// Round 9
// 157.134 us; speedup vs baseline: 1.1881x; 1.0294x over previous
//
#include <hip/hip_runtime.h>

#define NPTS 8192
#define NSLICE 64
#define SLICE_LEN (NPTS / NSLICE)
#define KNN 8
#define SURV_CAP 48
#define TQ 32  // queries per thresh block

typedef short bf16x8 __attribute__((ext_vector_type(8)));
typedef float f32x4 __attribute__((ext_vector_type(4)));

// bf16 round-to-nearest-even split helpers.
__device__ __forceinline__ unsigned short f2bf(float x) {
  unsigned int u = __float_as_uint(x);
  return (unsigned short)((u + 0x7FFF + ((u >> 16) & 1)) >> 16);
}
__device__ __forceinline__ float bf2f(unsigned short s) {
  return __uint_as_float(((unsigned int)s) << 16);
}

// Distance helpers. contract(off) pins the value DAG (r3 failure lesson).
// vals and collect consume IDENTICAL pts4 inputs -> bit-identical distances;
// inflated thresholds (thresh kernel) add a second safety net.
__device__ __forceinline__ float dist_exact(float qx, float qy, float qz,
                                            float q2, float px, float py,
                                            float pz, float p2) {
#pragma clang fp contract(off)
  float dot = __fmaf_rn(qz, pz, __fmaf_rn(qy, py, __fmul_rn(qx, px)));
  float t1 = __fadd_rn(q2, p2);
  return __fadd_rn(t1, __fmul_rn(-2.0f, dot));
}

__device__ __forceinline__ float norm2_exact(float x, float y, float z) {
#pragma clang fp contract(off)
  return __fadd_rn(__fadd_rn(__fmul_rn(x, x), __fmul_rn(y, y)),
                   __fmul_rn(z, z));
}

__device__ __forceinline__ float med3(float a, float b, float c) {
  return __builtin_amdgcn_fmed3f(a, b, c);
}

// Monotone (d, idx) -> f64 key (used only in the tiny final sort).
__device__ __forceinline__ double pack_key(float d, int idx) {
  unsigned int ub = __float_as_uint(d);
  ub ^= (((unsigned int)((int)ub >> 31)) | 0x80000000u);
  unsigned int lo = (ub << 13) | (unsigned int)idx;
  unsigned int hi = 0x3ff00000u | (ub >> 19);
  return __hiloint2double((int)hi, (int)lo);
}

#define KEY_DECL                                                            \
  const double KINF = __longlong_as_double(0x7ff0000000000000LL);           \
  double k0 = KINF, k1 = KINF, k2 = KINF, k3 = KINF, k4 = KINF, k5 = KINF,  \
         k6 = KINF, k7 = KINF;
#define KB1(s)                                                              \
  {                                                                         \
    double mn = fmin(carry, k##s);                                          \
    carry = fmax(carry, k##s);                                              \
    k##s = mn;                                                              \
  }
#define KEY_INSERT(key)                                                     \
  {                                                                         \
    double carry = (key);                                                   \
    KB1(0) KB1(1) KB1(2) KB1(3) KB1(4) KB1(5) KB1(6) KB1(7)                 \
  }

// f32 value-only sorted-8 insert: 7 med3 + 1 min, in-place descending.
#define VINS(dv)                                                            \
  {                                                                         \
    float dd = (dv);                                                        \
    v7 = med3(dd, v6, v7);                                                  \
    v6 = med3(dd, v5, v6);                                                  \
    v5 = med3(dd, v4, v5);                                                  \
    v4 = med3(dd, v3, v4);                                                  \
    v3 = med3(dd, v2, v3);                                                  \
    v2 = med3(dd, v1, v2);                                                  \
    v1 = med3(dd, v0, v1);                                                  \
    v0 = fminf(dd, v0);                                                     \
  }

#define VDECL                                                               \
  const float FINF = __uint_as_float(0x7f800000u);                          \
  float v0 = FINF, v1 = FINF, v2 = FINF, v3 = FINF, v4 = FINF, v5 = FINF,   \
        v6 = FINF, v7 = FINF;

// f32 value-only sorted-2 insert (slice-local): 2 ops.
#define VINS2(dv)                                                           \
  {                                                                         \
    float dd = (dv);                                                        \
    s1 = med3(dd, s0, s1);                                                  \
    s0 = fminf(dd, s0);                                                     \
  }

// ---------------------------------------------------------------------------
// Prep: W4 split (32768 ids) + pts4 pack + W2 transpose-split (id<8192).
// pts4 = (x,y,z,norm2) is the SINGLE source of candidate/query bits.
// W2t[col][k] bf16 hi/lo feeds gemm1's MFMA B-operand.
// ---------------------------------------------------------------------------
__global__ __launch_bounds__(256) void prep_kernel(
    const float* __restrict__ W4, const float* __restrict__ pts,
    const float* __restrict__ W2, unsigned short* __restrict__ W4ht,
    unsigned short* __restrict__ W4lt, unsigned short* __restrict__ W2th,
    unsigned short* __restrict__ W2tl, float4* __restrict__ pts4) {
  const int id = blockIdx.x * 256 + threadIdx.x;  // 32768
  const int k = id >> 8, c = id & 255;
  float v = W4[k * 256 + c];
  unsigned short hi = f2bf(v);
  unsigned short lo = f2bf(v - bf2f(hi));
  W4ht[c * 128 + k] = hi;
  W4lt[c * 128 + k] = lo;
  if (id < NPTS) {
    float x = pts[id * 3 + 0];
    float y = pts[id * 3 + 1];
    float z = pts[id * 3 + 2];
    pts4[id] = make_float4(x, y, z, norm2_exact(x, y, z));
    // W2 (64 x 128) -> transposed bf16 hi/lo [col 128][k 64]
    const int kk = id >> 7, cc = id & 127;
    float v2 = W2[kk * 128 + cc];
    unsigned short h2 = f2bf(v2);
    W2th[cc * 64 + kk] = h2;
    W2tl[cc * 64 + kk] = f2bf(v2 - bf2f(h2));
  }
}

// ---------------------------------------------------------------------------
// KNN A: per (query, slice of 128) keep the 2 smallest DISTANCE VALUES.
// Top-2 suffices: thresh needs per-slice mins (mask) + a pool whose
// 8th-smallest upper-bounds true v8. Output part_v[(slice*2+rank)*NPTS+q].
// ---------------------------------------------------------------------------
__global__ __launch_bounds__(256) void knn_vals_kernel(
    const float4* __restrict__ pts4, float* __restrict__ part_v) {
  __shared__ float4 sp[SLICE_LEN];
  const int t = threadIdx.x;
  const int q = blockIdx.x * 256 + t;
  const int jbase = blockIdx.y * SLICE_LEN;
  for (int p = t; p < SLICE_LEN; p += 256) sp[p] = pts4[jbase + p];
  __syncthreads();
  const float4 qp = pts4[q];
  const float qx = qp.x, qy = qp.y, qz = qp.z, q2 = qp.w;
  const float FINF = __uint_as_float(0x7f800000u);
  float s0 = FINF, s1 = FINF;
  for (int p = 0; p < SLICE_LEN; p += 8) {
    float4 c0 = sp[p + 0];
    float4 c1 = sp[p + 1];
    float4 c2 = sp[p + 2];
    float4 c3 = sp[p + 3];
    float4 c4 = sp[p + 4];
    float4 c5 = sp[p + 5];
    float4 c6 = sp[p + 6];
    float4 c7 = sp[p + 7];
    float d0 = dist_exact(qx, qy, qz, q2, c0.x, c0.y, c0.z, c0.w);
    float d1 = dist_exact(qx, qy, qz, q2, c1.x, c1.y, c1.z, c1.w);
    float d2 = dist_exact(qx, qy, qz, q2, c2.x, c2.y, c2.z, c2.w);
    float d3 = dist_exact(qx, qy, qz, q2, c3.x, c3.y, c3.z, c3.w);
    float d4 = dist_exact(qx, qy, qz, q2, c4.x, c4.y, c4.z, c4.w);
    float d5 = dist_exact(qx, qy, qz, q2, c5.x, c5.y, c5.z, c5.w);
    float d6 = dist_exact(qx, qy, qz, q2, c6.x, c6.y, c6.z, c6.w);
    float d7 = dist_exact(qx, qy, qz, q2, c7.x, c7.y, c7.z, c7.w);
    VINS2(d0);
    VINS2(d1);
    VINS2(d2);
    VINS2(d3);
    VINS2(d4);
    VINS2(d5);
    VINS2(d6);
    VINS2(d7);
  }
  float* o = &part_v[(size_t)(blockIdx.y * 2) * NPTS + q];
  o[0 * NPTS] = s0;
  o[1 * NPTS] = s1;
}

// ---------------------------------------------------------------------------
// KNN B (parallel merge): 8 threads/query over the 128-value pool (64x2).
// tau = pool 8th-smallest >= true v8. Inflated thresholds; collect gathers
// a small superset; final key-sort == jax.lax.top_k order.
// ---------------------------------------------------------------------------
__global__ __launch_bounds__(256) void knn_thresh_kernel(
    const float* __restrict__ part_v, float* __restrict__ thr,
    unsigned long long* __restrict__ mask) {
  __shared__ float v8s[TQ][8][9];   // [lq][chunk][rank]
  __shared__ float smin[TQ][65];    // slice mins
  const int t = threadIdx.x;
  const int lq = t >> 3, c = t & 7;
  const int q = blockIdx.x * TQ + lq;
  {
    VDECL;
#pragma unroll
    for (int s8 = 0; s8 < 8; ++s8) {
      const int s = c * 8 + s8;
      const float* col = &part_v[(size_t)(s * 2) * NPTS + q];
      float a0 = col[0 * (size_t)NPTS];
      float a1 = col[1 * (size_t)NPTS];
      smin[lq][s] = a0;
      VINS(a0);
      VINS(a1);
    }
    v8s[lq][c][0] = v0;
    v8s[lq][c][1] = v1;
    v8s[lq][c][2] = v2;
    v8s[lq][c][3] = v3;
    v8s[lq][c][4] = v4;
    v8s[lq][c][5] = v5;
    v8s[lq][c][6] = v6;
    v8s[lq][c][7] = v7;
  }
  __syncthreads();
  if (c == 0) {
    VDECL;
#pragma unroll
    for (int s = 0; s < 8; ++s) {
      VINS(v8s[lq][s][0]);
      VINS(v8s[lq][s][1]);
      VINS(v8s[lq][s][2]);
      VINS(v8s[lq][s][3]);
      VINS(v8s[lq][s][4]);
      VINS(v8s[lq][s][5]);
      VINS(v8s[lq][s][6]);
      VINS(v8s[lq][s][7]);
    }
    const float tcol = v7 + fabsf(v7) * 4e-5f + 1e-20f;
    const float tmask = v7 + fabsf(v7) * 8e-5f + 2e-20f;
    unsigned long long mk = 0;
#pragma unroll
    for (int s = 0; s < NSLICE; ++s) {
      if (smin[lq][s] <= tmask) mk |= (1ull << s);
    }
    thr[q] = tcol;
    mask[q] = mk;
  }
}

// ---------------------------------------------------------------------------
// KNN C (fused collect+final): one WAVE per query; scan marked slices only;
// survivors to LDS keybuf via atomics; lane 0 key-sorts and writes nbr.
// ---------------------------------------------------------------------------
__global__ __launch_bounds__(256) void knn_collect_kernel(
    const float4* __restrict__ pts4, const float* __restrict__ thr,
    const unsigned long long* __restrict__ mask, int* __restrict__ nbr) {
  __shared__ double keybuf[4][SURV_CAP];
  __shared__ int scnt[4];
  const int t = threadIdx.x;
  const int wv = t >> 6;
  const int lane = t & 63;
  const int q = blockIdx.x * 4 + wv;
  if (lane == 0) scnt[wv] = 0;
  __syncthreads();
  const float4 qp = pts4[q];
  const float qx = qp.x, qy = qp.y, qz = qp.z, q2 = qp.w;
  const float thrq = thr[q];
  unsigned long long m = mask[q];
  while (m) {
    const int s = (int)__ffsll(m) - 1;
    m &= m - 1;
    const int base = s * SLICE_LEN;
#pragma unroll
    for (int r = 0; r < SLICE_LEN / 64; ++r) {
      const int j = base + r * 64 + lane;
      const float4 cp = pts4[j];
      const float d = dist_exact(qx, qy, qz, q2, cp.x, cp.y, cp.z, cp.w);
      if (d <= thrq) {
        int slot = atomicAdd(&scnt[wv], 1);
        if (slot < SURV_CAP) keybuf[wv][slot] = pack_key(d, j);
      }
    }
  }
  __syncthreads();
  if (lane == 0) {
    int c = scnt[wv];
    if (c > SURV_CAP) c = SURV_CAP;
    KEY_DECL;
    for (int u = 0; u < c; ++u) {
      KEY_INSERT(keybuf[wv][u]);
    }
    int* o = &nbr[q * KNN];
    o[0] = __double2loint(k0) & 0x1fff;
    o[1] = __double2loint(k1) & 0x1fff;
    o[2] = __double2loint(k2) & 0x1fff;
    o[3] = __double2loint(k3) & 0x1fff;
    o[4] = __double2loint(k4) & 0x1fff;
    o[5] = __double2loint(k5) & 0x1fff;
    o[6] = __double2loint(k6) & 0x1fff;
    o[7] = __double2loint(k7) & 0x1fff;
  }
}

// ---------------------------------------------------------------------------
// Fused EdgeConv1 (MFMA): H1 = relu(e@W1+b1) exact fp32 (K=6), split to
// bf16 hi/lo in LDS; Y-tile = H1@W2 via split-bf16 3-pass MFMA (gemm2's
// verified pattern: D = Hh*Wh + Hh*Wl + Hl*Wh); in-register max8 + b2 +
// relu -> y (8192x128). 64 edges x 64 cols per block; wave w owns rows
// [w*16, w*16+16). Stride 72 ushort => 2-way LDS bank alias only (free).
// ---------------------------------------------------------------------------
__global__ __launch_bounds__(256) void gemm1_fused_kernel(
    const float* __restrict__ pts, const int* __restrict__ nbr,
    const float* __restrict__ W1, const float* __restrict__ b1,
    const unsigned short* __restrict__ W2th,
    const unsigned short* __restrict__ W2tl, const float* __restrict__ b2,
    float* __restrict__ y) {
  __shared__ float es[64][6];
  __shared__ float W1s[6][64];
  __shared__ float b1s[64];
  __shared__ unsigned short H1h[64 * 72];
  __shared__ unsigned short H1l[64 * 72];
  __shared__ unsigned short Wth[64 * 72];
  __shared__ unsigned short Wtl[64 * 72];
  const int t = threadIdx.x;
  const int rowBase = blockIdx.y * 64;
  const int colBase = blockIdx.x * 64;

  for (int idx = t; idx < 384; idx += 256) W1s[idx >> 6][idx & 63] = W1[idx];
  if (t < 64) b1s[t] = b1[t];
  {
    // Stage W2t band: 64 cols x 64 k, bf16 hi/lo.
    const int colloc = t >> 2, kq = (t & 3) * 16;
    const size_t src = (size_t)(colBase + colloc) * 64 + kq;
    *(uint4*)&Wth[colloc * 72 + kq] = *(const uint4*)&W2th[src];
    *(uint4*)&Wth[colloc * 72 + kq + 8] = *(const uint4*)&W2th[src + 8];
    *(uint4*)&Wtl[colloc * 72 + kq] = *(const uint4*)&W2tl[src];
    *(uint4*)&Wtl[colloc * 72 + kq + 8] = *(const uint4*)&W2tl[src + 8];
  }
  if (t < 64) {
    int e = rowBase + t;
    int i = e >> 3;
    int j = nbr[e];
    float xi0 = pts[i * 3], xi1 = pts[i * 3 + 1], xi2 = pts[i * 3 + 2];
    es[t][0] = xi0;
    es[t][1] = xi1;
    es[t][2] = xi2;
    es[t][3] = pts[j * 3] - xi0;
    es[t][4] = pts[j * 3 + 1] - xi1;
    es[t][5] = pts[j * 3 + 2] - xi2;
  }
  __syncthreads();

  {
    // H1 compute (fp32 exact) + bf16 hi/lo split into LDS.
    const int e = t & 63, k0 = (t >> 6) * 16;
    const float f0 = es[e][0], f1 = es[e][1], f2 = es[e][2];
    const float f3 = es[e][3], f4 = es[e][4], f5 = es[e][5];
    float h[16];
#pragma unroll
    for (int k = 0; k < 16; ++k) {
      int c = k0 + k;
      float v = b1s[c];
      v = fmaf(f0, W1s[0][c], v);
      v = fmaf(f1, W1s[1][c], v);
      v = fmaf(f2, W1s[2][c], v);
      v = fmaf(f3, W1s[3][c], v);
      v = fmaf(f4, W1s[4][c], v);
      v = fmaf(f5, W1s[5][c], v);
      h[k] = fmaxf(v, 0.0f);
    }
    unsigned int hp[8], lp[8];
#pragma unroll
    for (int u = 0; u < 8; ++u) {
      unsigned short h0 = f2bf(h[2 * u]), h1 = f2bf(h[2 * u + 1]);
      hp[u] = (unsigned int)h0 | ((unsigned int)h1 << 16);
      unsigned short l0 = f2bf(h[2 * u] - bf2f(h0));
      unsigned short l1 = f2bf(h[2 * u + 1] - bf2f(h1));
      lp[u] = (unsigned int)l0 | ((unsigned int)l1 << 16);
    }
    *(uint4*)&H1h[e * 72 + k0] = make_uint4(hp[0], hp[1], hp[2], hp[3]);
    *(uint4*)&H1h[e * 72 + k0 + 8] = make_uint4(hp[4], hp[5], hp[6], hp[7]);
    *(uint4*)&H1l[e * 72 + k0] = make_uint4(lp[0], lp[1], lp[2], lp[3]);
    *(uint4*)&H1l[e * 72 + k0 + 8] = make_uint4(lp[4], lp[5], lp[6], lp[7]);
  }
  __syncthreads();

  const int lane = t & 63, w = t >> 6;
  const int qq = lane >> 4, nidx = lane & 15;
  f32x4 acc[4];
#pragma unroll
  for (int nt = 0; nt < 4; ++nt) acc[nt] = (f32x4){0.f, 0.f, 0.f, 0.f};
  bf16x8 ah0, ah1, al0, al1;
  {
    const int row = w * 16 + nidx;
    ah0 = *(const bf16x8*)&H1h[row * 72 + qq * 8];
    ah1 = *(const bf16x8*)&H1h[row * 72 + 32 + qq * 8];
    al0 = *(const bf16x8*)&H1l[row * 72 + qq * 8];
    al1 = *(const bf16x8*)&H1l[row * 72 + 32 + qq * 8];
  }
#pragma unroll
  for (int nt = 0; nt < 4; ++nt) {
    const int col = nt * 16 + nidx;
    bf16x8 bh0 = *(const bf16x8*)&Wth[col * 72 + qq * 8];
    bf16x8 bh1 = *(const bf16x8*)&Wth[col * 72 + 32 + qq * 8];
    bf16x8 bl0 = *(const bf16x8*)&Wtl[col * 72 + qq * 8];
    bf16x8 bl1 = *(const bf16x8*)&Wtl[col * 72 + 32 + qq * 8];
    acc[nt] = __builtin_amdgcn_mfma_f32_16x16x32_bf16(ah0, bh0, acc[nt], 0, 0, 0);
    acc[nt] = __builtin_amdgcn_mfma_f32_16x16x32_bf16(ah1, bh1, acc[nt], 0, 0, 0);
    acc[nt] = __builtin_amdgcn_mfma_f32_16x16x32_bf16(ah0, bl0, acc[nt], 0, 0, 0);
    acc[nt] = __builtin_amdgcn_mfma_f32_16x16x32_bf16(ah1, bl1, acc[nt], 0, 0, 0);
    acc[nt] = __builtin_amdgcn_mfma_f32_16x16x32_bf16(al0, bh0, acc[nt], 0, 0, 0);
    acc[nt] = __builtin_amdgcn_mfma_f32_16x16x32_bf16(al1, bh1, acc[nt], 0, 0, 0);
  }

  // Epilogue: C/D row = qq*4+reg (local), col = nt*16+nidx. Max over the
  // lane's 4 rows, then shfl_xor(16) pairs qq^1 -> max over 8 edge rows.
  const int pt = blockIdx.y * 8 + 2 * w + (qq >> 1);
#pragma unroll
  for (int nt = 0; nt < 4; ++nt) {
    f32x4 a = acc[nt];
    float m = fmaxf(fmaxf(a[0], a[1]), fmaxf(a[2], a[3]));
    float o = fmaxf(m, __shfl_xor(m, 16, 64));
    if ((qq & 1) == 0) {
      int cg = colBase + nt * 16 + nidx;
      y[(size_t)pt * 128 + cg] = fmaxf(o + b2[cg], 0.0f);
    }
  }
}

// ---------------------------------------------------------------------------
// AC = y @ [W3top|W3bot] (+b3 on cols<128). 64x64 GEMM (8192x128x256).
// B staged DIRECTLY from W3 (col band lies in one half of the concat).
// ---------------------------------------------------------------------------
__global__ __launch_bounds__(256) void gemm_ac_kernel(
    const float* __restrict__ A, const float* __restrict__ W3,
    const float* __restrict__ bias, float* __restrict__ out) {
  __shared__ float As[64][64];
  __shared__ float Bs[64][64];
  const int t = threadIdx.x;
  const int tx = t & 15, ty = t >> 4;
  const int rowBase = blockIdx.y * 64;
  const int colBase = blockIdx.x * 64;
  const float4* A4 = (const float4*)A;
  float acc[4][4] = {};
  const int K = 128, Nglob = 256;

  for (int k0 = 0; k0 < K; k0 += 64) {
#pragma unroll
    for (int it = 0; it < 4; ++it) {
      int idx = it * 256 + t;
      int row = idx & 63, kq = idx >> 6;
      float4 av = A4[(size_t)(rowBase + row) * (K >> 2) + (k0 >> 2) + kq];
      As[kq * 4 + 0][row] = av.x;
      As[kq * 4 + 1][row] = av.y;
      As[kq * 4 + 2][row] = av.z;
      As[kq * 4 + 3][row] = av.w;
    }
#pragma unroll
    for (int it = 0; it < 4; ++it) {
      int idx = it * 256 + t;
      int cq = idx & 15, kr = idx >> 4;
      const float* src =
          (colBase < 128)
              ? &W3[(size_t)(k0 + kr) * 128 + colBase]
              : &W3[(size_t)(128 + k0 + kr) * 128 + (colBase - 128)];
      float4 bv = *(const float4*)&src[cq * 4];
      *(float4*)&Bs[kr][cq * 4] = bv;
    }
    __syncthreads();
#pragma unroll 8
    for (int k = 0; k < 64; ++k) {
      float4 a = *(const float4*)&As[k][ty * 4];
      float4 b = *(const float4*)&Bs[k][tx * 4];
      const float ar[4] = {a.x, a.y, a.z, a.w};
      const float br[4] = {b.x, b.y, b.z, b.w};
#pragma unroll
      for (int i = 0; i < 4; ++i)
#pragma unroll
        for (int jj = 0; jj < 4; ++jj)
          acc[i][jj] = fmaf(ar[i], br[jj], acc[i][jj]);
    }
    __syncthreads();
  }

#pragma unroll
  for (int i = 0; i < 4; ++i) {
    float4 o;
    float* oa = (float*)&o;
#pragma unroll
    for (int jj = 0; jj < 4; ++jj) {
      float v = acc[i][jj];
      int cg = colBase + tx * 4 + jj;
      if (cg < 128) v += bias[cg];
      oa[jj] = v;
    }
    *(float4*)&out[(size_t)(rowBase + ty * 4 + i) * Nglob + colBase + tx * 4] =
        o;
  }
}

// ---------------------------------------------------------------------------
// MFMA EdgeConv2 second layer (split-bf16), as R7 (verified):
// D = Hh*Wh + Hh*Wl + Hl*Wh in fp32 MFMA acc; in-register segmax + b4.
// ---------------------------------------------------------------------------
__global__ __launch_bounds__(256) void gemm2_mfma_kernel(
    const float* __restrict__ AC, const int* __restrict__ nbr,
    const unsigned short* __restrict__ W4ht,
    const unsigned short* __restrict__ W4lt, const float* __restrict__ b4,
    float* __restrict__ out) {
  __shared__ unsigned short H2h[128 * 40];
  __shared__ unsigned short H2l[128 * 40];
  __shared__ unsigned short Wth[128 * 40];
  __shared__ unsigned short Wtl[128 * 40];
  const int t = threadIdx.x;
  const int rowBase = blockIdx.y * 128;
  const int colBase = blockIdx.x * 128;
  const int eloc = t >> 1, hh = t & 1;
  const int kb = hh * 16;
  const int edge = rowBase + eloc;
  const int ip = edge >> 3;
  const int jp = nbr[edge];
  const float* ai_p = AC + (size_t)ip * 256;
  const float* ci_p = ai_p + 128;
  const float* cj_p = AC + (size_t)jp * 256 + 128;
  const int lane = t & 63;
  const int w = t >> 6;
  const int q = lane >> 4;
  const int nidx = lane & 15;

  f32x4 acc[2][8];
#pragma unroll
  for (int mt = 0; mt < 2; ++mt)
#pragma unroll
    for (int nt = 0; nt < 8; ++nt) acc[mt][nt] = (f32x4){0.f, 0.f, 0.f, 0.f};

  for (int p = 0; p < 4; ++p) {
    const int k0 = p * 32;
    {
      float h2[16];
      const float4* a4 = (const float4*)(ai_p + k0 + kb);
      const float4* c4 = (const float4*)(ci_p + k0 + kb);
      const float4* d4 = (const float4*)(cj_p + k0 + kb);
#pragma unroll
      for (int u = 0; u < 4; ++u) {
        float4 a = a4[u], c = c4[u], d = d4[u];
        h2[u * 4 + 0] = fmaxf(a.x + d.x - c.x, 0.f);
        h2[u * 4 + 1] = fmaxf(a.y + d.y - c.y, 0.f);
        h2[u * 4 + 2] = fmaxf(a.z + d.z - c.z, 0.f);
        h2[u * 4 + 3] = fmaxf(a.w + d.w - c.w, 0.f);
      }
      unsigned int hp[8], lp[8];
#pragma unroll
      for (int u = 0; u < 8; ++u) {
        unsigned short h0 = f2bf(h2[2 * u]), h1 = f2bf(h2[2 * u + 1]);
        hp[u] = (unsigned int)h0 | ((unsigned int)h1 << 16);
        unsigned short l0 = f2bf(h2[2 * u] - bf2f(h0));
        unsigned short l1 = f2bf(h2[2 * u + 1] - bf2f(h1));
        lp[u] = (unsigned int)l0 | ((unsigned int)l1 << 16);
      }
      *(uint4*)&H2h[eloc * 40 + kb] = make_uint4(hp[0], hp[1], hp[2], hp[3]);
      *(uint4*)&H2h[eloc * 40 + kb + 8] =
          make_uint4(hp[4], hp[5], hp[6], hp[7]);
      *(uint4*)&H2l[eloc * 40 + kb] = make_uint4(lp[0], lp[1], lp[2], lp[3]);
      *(uint4*)&H2l[eloc * 40 + kb + 8] =
          make_uint4(lp[4], lp[5], lp[6], lp[7]);
    }
    {
      const size_t src = (size_t)(colBase + eloc) * 128 + k0 + kb;
      *(uint4*)&Wth[eloc * 40 + kb] = *(const uint4*)&W4ht[src];
      *(uint4*)&Wth[eloc * 40 + kb + 8] = *(const uint4*)&W4ht[src + 8];
      *(uint4*)&Wtl[eloc * 40 + kb] = *(const uint4*)&W4lt[src];
      *(uint4*)&Wtl[eloc * 40 + kb + 8] = *(const uint4*)&W4lt[src + 8];
    }
    __syncthreads();
    bf16x8 ah[2], al[2];
#pragma unroll
    for (int mt = 0; mt < 2; ++mt) {
      int row = w * 32 + mt * 16 + nidx;
      ah[mt] = *(const bf16x8*)&H2h[row * 40 + q * 8];
      al[mt] = *(const bf16x8*)&H2l[row * 40 + q * 8];
    }
#pragma unroll
    for (int nt = 0; nt < 8; ++nt) {
      int col = nt * 16 + nidx;
      bf16x8 bh = *(const bf16x8*)&Wth[col * 40 + q * 8];
      bf16x8 bl = *(const bf16x8*)&Wtl[col * 40 + q * 8];
#pragma unroll
      for (int mt = 0; mt < 2; ++mt) {
        acc[mt][nt] = __builtin_amdgcn_mfma_f32_16x16x32_bf16(
            ah[mt], bh, acc[mt][nt], 0, 0, 0);
        acc[mt][nt] = __builtin_amdgcn_mfma_f32_16x16x32_bf16(
            ah[mt], bl, acc[mt][nt], 0, 0, 0);
        acc[mt][nt] = __builtin_amdgcn_mfma_f32_16x16x32_bf16(
            al[mt], bh, acc[mt][nt], 0, 0, 0);
      }
    }
    __syncthreads();
  }

#pragma unroll
  for (int mt = 0; mt < 2; ++mt) {
    const int ebase = rowBase + w * 32 + mt * 16;
    const int pt0 = ebase >> 3;
#pragma unroll
    for (int nt = 0; nt < 8; ++nt) {
      f32x4 a = acc[mt][nt];
      float m = fmaxf(fmaxf(a[0], a[1]), fmaxf(a[2], a[3]));
      float o = fmaxf(m, __shfl_xor(m, 16, 64));
      int cg = colBase + nt * 16 + nidx;
      if (q == 0) {
        out[(size_t)pt0 * 256 + cg] = o + b4[cg];
      } else if (q == 2) {
        out[(size_t)(pt0 + 1) * 256 + cg] = o + b4[cg];
      }
    }
  }
}

extern "C" void kernel_launch(void* const* d_in, const int* in_sizes, int n_in,
                              void* d_out, int out_size, void* d_ws,
                              size_t ws_size, hipStream_t stream) {
  const float* pts = (const float*)d_in[0];
  const float* W1 = (const float*)d_in[1];
  const float* b1 = (const float*)d_in[2];
  const float* W2 = (const float*)d_in[3];
  const float* b2 = (const float*)d_in[4];
  const float* W3 = (const float*)d_in[5];
  const float* b3 = (const float*)d_in[6];
  const float* W4 = (const float*)d_in[7];
  const float* b4 = (const float*)d_in[8];
  float* out = (float*)d_out;

  // Workspace layout (floats), lifetime-overlapped:
  //   part_v [0, 1048576)          : vals->thresh (within AC region)
  //   thr    [4194304, +8192)      : thresh->collect
  //   nbr    [4202496, +65536)     : collect->gemm1/gemm2
  //   y      [4268032, +1048576)   : gemm1->gemm_ac
  //   mask   [5316608, +16384)     : thresh->collect (u64[8192])
  //   W4ht   [5332992, +16384)
  //   W4lt   [5349376, +16384)
  //   pts4   [5365760, +32768)     : prep->vals/collect (f4[8192])
  //   W2th   [5398528, +4096)      : prep->gemm1 (ushort[8192])
  //   W2tl   [5402624, +4096)      : prep->gemm1 (ushort[8192])
  //   AC = [0, 2097152) (written after part_v is dead)
  float* w = (float*)d_ws;
  float* part_v = w;
  float* thr = w + 4194304;
  int* nbr = (int*)(w + 4202496);
  float* y = w + 4268032;
  unsigned long long* mask = (unsigned long long*)(w + 5316608);
  unsigned short* W4ht = (unsigned short*)(w + 5332992);
  unsigned short* W4lt = (unsigned short*)(w + 5349376);
  float4* pts4 = (float4*)(w + 5365760);
  unsigned short* W2th = (unsigned short*)(w + 5398528);
  unsigned short* W2tl = (unsigned short*)(w + 5402624);
  float* AC = w;

  // 0. Prep: W4 bf16-split + pts4 pack + W2 transpose-split (fused).
  prep_kernel<<<128, 256, 0, stream>>>(W4, pts, W2, W4ht, W4lt, W2th, W2tl,
                                       pts4);

  // 1. KNN: slice top-2 values -> parallel pool-merge thresh -> collect.
  knn_vals_kernel<<<dim3(32, NSLICE), 256, 0, stream>>>(pts4, part_v);
  knn_thresh_kernel<<<NPTS / TQ, 256, 0, stream>>>(part_v, thr, mask);
  knn_collect_kernel<<<2048, 256, 0, stream>>>(pts4, thr, mask, nbr);

  // 2. EdgeConv1 (MFMA H1@W2 + max8 + b2 + relu)
  gemm1_fused_kernel<<<dim3(2, 1024), 256, 0, stream>>>(pts, nbr, W1, b1,
                                                        W2th, W2tl, b2, y);

  // 3. EdgeConv2: AC = y@[W3|W3] (+b3), then MFMA H2+GEMM+max8+b4 -> out
  gemm_ac_kernel<<<dim3(4, 128), 256, 0, stream>>>(y, W3, b3, AC);
  gemm2_mfma_kernel<<<dim3(2, 512), 256, 0, stream>>>(AC, nbr, W4ht, W4lt, b4,
                                                      out);
}

// Round 10
// 156.385 us; speedup vs baseline: 1.1938x; 1.0048x over previous
//
#include <hip/hip_runtime.h>

#define NPTS 8192
#define NSLICE 64
#define SLICE_LEN (NPTS / NSLICE)
#define KNN 8
#define SURV_CAP 48
#define TQ 32  // queries per thresh block

typedef short bf16x8 __attribute__((ext_vector_type(8)));
typedef float f32x4 __attribute__((ext_vector_type(4)));

// bf16 round-to-nearest-even split helpers.
__device__ __forceinline__ unsigned short f2bf(float x) {
  unsigned int u = __float_as_uint(x);
  return (unsigned short)((u + 0x7FFF + ((u >> 16) & 1)) >> 16);
}
__device__ __forceinline__ float bf2f(unsigned short s) {
  return __uint_as_float(((unsigned int)s) << 16);
}

// Distance helpers. contract(off) pins the value DAG (r3 failure lesson).
// vals and collect consume IDENTICAL pts4 inputs -> bit-identical distances;
// inflated thresholds (thresh kernel) add a second safety net.
__device__ __forceinline__ float dist_exact(float qx, float qy, float qz,
                                            float q2, float px, float py,
                                            float pz, float p2) {
#pragma clang fp contract(off)
  float dot = __fmaf_rn(qz, pz, __fmaf_rn(qy, py, __fmul_rn(qx, px)));
  float t1 = __fadd_rn(q2, p2);
  return __fadd_rn(t1, __fmul_rn(-2.0f, dot));
}

__device__ __forceinline__ float norm2_exact(float x, float y, float z) {
#pragma clang fp contract(off)
  return __fadd_rn(__fadd_rn(__fmul_rn(x, x), __fmul_rn(y, y)),
                   __fmul_rn(z, z));
}

__device__ __forceinline__ float med3(float a, float b, float c) {
  return __builtin_amdgcn_fmed3f(a, b, c);
}

// Monotone (d, idx) -> f64 key (used only in the tiny final sort).
__device__ __forceinline__ double pack_key(float d, int idx) {
  unsigned int ub = __float_as_uint(d);
  ub ^= (((unsigned int)((int)ub >> 31)) | 0x80000000u);
  unsigned int lo = (ub << 13) | (unsigned int)idx;
  unsigned int hi = 0x3ff00000u | (ub >> 19);
  return __hiloint2double((int)hi, (int)lo);
}

#define KEY_DECL                                                            \
  const double KINF = __longlong_as_double(0x7ff0000000000000LL);           \
  double k0 = KINF, k1 = KINF, k2 = KINF, k3 = KINF, k4 = KINF, k5 = KINF,  \
         k6 = KINF, k7 = KINF;
#define KB1(s)                                                              \
  {                                                                         \
    double mn = fmin(carry, k##s);                                          \
    carry = fmax(carry, k##s);                                              \
    k##s = mn;                                                              \
  }
#define KEY_INSERT(key)                                                     \
  {                                                                         \
    double carry = (key);                                                   \
    KB1(0) KB1(1) KB1(2) KB1(3) KB1(4) KB1(5) KB1(6) KB1(7)                 \
  }

// f32 value-only sorted-8 insert: 7 med3 + 1 min, in-place descending.
#define VINS(dv)                                                            \
  {                                                                         \
    float dd = (dv);                                                        \
    v7 = med3(dd, v6, v7);                                                  \
    v6 = med3(dd, v5, v6);                                                  \
    v5 = med3(dd, v4, v5);                                                  \
    v4 = med3(dd, v3, v4);                                                  \
    v3 = med3(dd, v2, v3);                                                  \
    v2 = med3(dd, v1, v2);                                                  \
    v1 = med3(dd, v0, v1);                                                  \
    v0 = fminf(dd, v0);                                                     \
  }

#define VDECL                                                               \
  const float FINF = __uint_as_float(0x7f800000u);                          \
  float v0 = FINF, v1 = FINF, v2 = FINF, v3 = FINF, v4 = FINF, v5 = FINF,   \
        v6 = FINF, v7 = FINF;

// f32 value-only sorted-2 insert (slice-local): 2 ops.
#define VINS2(dv)                                                           \
  {                                                                         \
    float dd = (dv);                                                        \
    s1 = med3(dd, s0, s1);                                                  \
    s0 = fminf(dd, s0);                                                     \
  }

// ---------------------------------------------------------------------------
// Prep: W4 split + Wcat transpose-split (all 32768 ids) + pts4 pack + W2
// transpose-split (id<8192). pts4 = (x,y,z,norm2) is the SINGLE source of
// candidate/query bits. W2t/W3t bf16 hi/lo feed gemm1/gemm_ac MFMA B-ops.
// Wcat[k][c] = c<128 ? W3[k][c] : W3[128+k][c-128]  (k<128, c<256).
// ---------------------------------------------------------------------------
__global__ __launch_bounds__(256) void prep_kernel(
    const float* __restrict__ W4, const float* __restrict__ pts,
    const float* __restrict__ W2, const float* __restrict__ W3,
    unsigned short* __restrict__ W4ht, unsigned short* __restrict__ W4lt,
    unsigned short* __restrict__ W2th, unsigned short* __restrict__ W2tl,
    unsigned short* __restrict__ W3th, unsigned short* __restrict__ W3tl,
    float4* __restrict__ pts4) {
  const int id = blockIdx.x * 256 + threadIdx.x;  // 32768
  const int k = id >> 8, c = id & 255;
  {
    float v = W4[k * 256 + c];
    unsigned short hi = f2bf(v);
    unsigned short lo = f2bf(v - bf2f(hi));
    W4ht[c * 128 + k] = hi;
    W4lt[c * 128 + k] = lo;
  }
  {
    float v3 = (c < 128) ? W3[k * 128 + c] : W3[(128 + k) * 128 + (c - 128)];
    unsigned short h3 = f2bf(v3);
    W3th[c * 128 + k] = h3;
    W3tl[c * 128 + k] = f2bf(v3 - bf2f(h3));
  }
  if (id < NPTS) {
    float x = pts[id * 3 + 0];
    float y = pts[id * 3 + 1];
    float z = pts[id * 3 + 2];
    pts4[id] = make_float4(x, y, z, norm2_exact(x, y, z));
    // W2 (64 x 128) -> transposed bf16 hi/lo [col 128][k 64]
    const int kk = id >> 7, cc = id & 127;
    float v2 = W2[kk * 128 + cc];
    unsigned short h2 = f2bf(v2);
    W2th[cc * 64 + kk] = h2;
    W2tl[cc * 64 + kk] = f2bf(v2 - bf2f(h2));
  }
}

// ---------------------------------------------------------------------------
// KNN A: per (query, slice of 128) keep the 2 smallest DISTANCE VALUES.
// Top-2 suffices: thresh needs per-slice mins (mask) + a pool whose
// 8th-smallest upper-bounds true v8. Output part_v[(slice*2+rank)*NPTS+q].
// ---------------------------------------------------------------------------
__global__ __launch_bounds__(256) void knn_vals_kernel(
    const float4* __restrict__ pts4, float* __restrict__ part_v) {
  __shared__ float4 sp[SLICE_LEN];
  const int t = threadIdx.x;
  const int q = blockIdx.x * 256 + t;
  const int jbase = blockIdx.y * SLICE_LEN;
  for (int p = t; p < SLICE_LEN; p += 256) sp[p] = pts4[jbase + p];
  __syncthreads();
  const float4 qp = pts4[q];
  const float qx = qp.x, qy = qp.y, qz = qp.z, q2 = qp.w;
  const float FINF = __uint_as_float(0x7f800000u);
  float s0 = FINF, s1 = FINF;
  for (int p = 0; p < SLICE_LEN; p += 8) {
    float4 c0 = sp[p + 0];
    float4 c1 = sp[p + 1];
    float4 c2 = sp[p + 2];
    float4 c3 = sp[p + 3];
    float4 c4 = sp[p + 4];
    float4 c5 = sp[p + 5];
    float4 c6 = sp[p + 6];
    float4 c7 = sp[p + 7];
    float d0 = dist_exact(qx, qy, qz, q2, c0.x, c0.y, c0.z, c0.w);
    float d1 = dist_exact(qx, qy, qz, q2, c1.x, c1.y, c1.z, c1.w);
    float d2 = dist_exact(qx, qy, qz, q2, c2.x, c2.y, c2.z, c2.w);
    float d3 = dist_exact(qx, qy, qz, q2, c3.x, c3.y, c3.z, c3.w);
    float d4 = dist_exact(qx, qy, qz, q2, c4.x, c4.y, c4.z, c4.w);
    float d5 = dist_exact(qx, qy, qz, q2, c5.x, c5.y, c5.z, c5.w);
    float d6 = dist_exact(qx, qy, qz, q2, c6.x, c6.y, c6.z, c6.w);
    float d7 = dist_exact(qx, qy, qz, q2, c7.x, c7.y, c7.z, c7.w);
    VINS2(d0);
    VINS2(d1);
    VINS2(d2);
    VINS2(d3);
    VINS2(d4);
    VINS2(d5);
    VINS2(d6);
    VINS2(d7);
  }
  float* o = &part_v[(size_t)(blockIdx.y * 2) * NPTS + q];
  o[0 * NPTS] = s0;
  o[1 * NPTS] = s1;
}

// ---------------------------------------------------------------------------
// KNN B (parallel merge): 8 threads/query over the 128-value pool (64x2).
// tau = pool 8th-smallest >= true v8. Inflated thresholds; collect gathers
// a small superset; final key-sort == jax.lax.top_k order.
// ---------------------------------------------------------------------------
__global__ __launch_bounds__(256) void knn_thresh_kernel(
    const float* __restrict__ part_v, float* __restrict__ thr,
    unsigned long long* __restrict__ mask) {
  __shared__ float v8s[TQ][8][9];   // [lq][chunk][rank]
  __shared__ float smin[TQ][65];    // slice mins
  const int t = threadIdx.x;
  const int lq = t >> 3, c = t & 7;
  const int q = blockIdx.x * TQ + lq;
  {
    VDECL;
#pragma unroll
    for (int s8 = 0; s8 < 8; ++s8) {
      const int s = c * 8 + s8;
      const float* col = &part_v[(size_t)(s * 2) * NPTS + q];
      float a0 = col[0 * (size_t)NPTS];
      float a1 = col[1 * (size_t)NPTS];
      smin[lq][s] = a0;
      VINS(a0);
      VINS(a1);
    }
    v8s[lq][c][0] = v0;
    v8s[lq][c][1] = v1;
    v8s[lq][c][2] = v2;
    v8s[lq][c][3] = v3;
    v8s[lq][c][4] = v4;
    v8s[lq][c][5] = v5;
    v8s[lq][c][6] = v6;
    v8s[lq][c][7] = v7;
  }
  __syncthreads();
  if (c == 0) {
    VDECL;
#pragma unroll
    for (int s = 0; s < 8; ++s) {
      VINS(v8s[lq][s][0]);
      VINS(v8s[lq][s][1]);
      VINS(v8s[lq][s][2]);
      VINS(v8s[lq][s][3]);
      VINS(v8s[lq][s][4]);
      VINS(v8s[lq][s][5]);
      VINS(v8s[lq][s][6]);
      VINS(v8s[lq][s][7]);
    }
    const float tcol = v7 + fabsf(v7) * 4e-5f + 1e-20f;
    const float tmask = v7 + fabsf(v7) * 8e-5f + 2e-20f;
    unsigned long long mk = 0;
#pragma unroll
    for (int s = 0; s < NSLICE; ++s) {
      if (smin[lq][s] <= tmask) mk |= (1ull << s);
    }
    thr[q] = tcol;
    mask[q] = mk;
  }
}

// ---------------------------------------------------------------------------
// KNN C (fused collect+final): one WAVE per query; scan marked slices only;
// survivors to LDS keybuf via atomics; lane 0 key-sorts and writes nbr.
// ---------------------------------------------------------------------------
__global__ __launch_bounds__(256) void knn_collect_kernel(
    const float4* __restrict__ pts4, const float* __restrict__ thr,
    const unsigned long long* __restrict__ mask, int* __restrict__ nbr) {
  __shared__ double keybuf[4][SURV_CAP];
  __shared__ int scnt[4];
  const int t = threadIdx.x;
  const int wv = t >> 6;
  const int lane = t & 63;
  const int q = blockIdx.x * 4 + wv;
  if (lane == 0) scnt[wv] = 0;
  __syncthreads();
  const float4 qp = pts4[q];
  const float qx = qp.x, qy = qp.y, qz = qp.z, q2 = qp.w;
  const float thrq = thr[q];
  unsigned long long m = mask[q];
  while (m) {
    const int s = (int)__ffsll(m) - 1;
    m &= m - 1;
    const int base = s * SLICE_LEN;
#pragma unroll
    for (int r = 0; r < SLICE_LEN / 64; ++r) {
      const int j = base + r * 64 + lane;
      const float4 cp = pts4[j];
      const float d = dist_exact(qx, qy, qz, q2, cp.x, cp.y, cp.z, cp.w);
      if (d <= thrq) {
        int slot = atomicAdd(&scnt[wv], 1);
        if (slot < SURV_CAP) keybuf[wv][slot] = pack_key(d, j);
      }
    }
  }
  __syncthreads();
  if (lane == 0) {
    int c = scnt[wv];
    if (c > SURV_CAP) c = SURV_CAP;
    KEY_DECL;
    for (int u = 0; u < c; ++u) {
      KEY_INSERT(keybuf[wv][u]);
    }
    int* o = &nbr[q * KNN];
    o[0] = __double2loint(k0) & 0x1fff;
    o[1] = __double2loint(k1) & 0x1fff;
    o[2] = __double2loint(k2) & 0x1fff;
    o[3] = __double2loint(k3) & 0x1fff;
    o[4] = __double2loint(k4) & 0x1fff;
    o[5] = __double2loint(k5) & 0x1fff;
    o[6] = __double2loint(k6) & 0x1fff;
    o[7] = __double2loint(k7) & 0x1fff;
  }
}

// ---------------------------------------------------------------------------
// Fused EdgeConv1 (MFMA): H1 = relu(e@W1+b1) exact fp32 (K=6), split to
// bf16 hi/lo in LDS; Y-tile = H1@W2 via split-bf16 3-pass MFMA; in-register
// max8 + b2 + relu -> y (8192x128). As r9 (verified).
// ---------------------------------------------------------------------------
__global__ __launch_bounds__(256) void gemm1_fused_kernel(
    const float* __restrict__ pts, const int* __restrict__ nbr,
    const float* __restrict__ W1, const float* __restrict__ b1,
    const unsigned short* __restrict__ W2th,
    const unsigned short* __restrict__ W2tl, const float* __restrict__ b2,
    float* __restrict__ y) {
  __shared__ float es[64][6];
  __shared__ float W1s[6][64];
  __shared__ float b1s[64];
  __shared__ unsigned short H1h[64 * 72];
  __shared__ unsigned short H1l[64 * 72];
  __shared__ unsigned short Wth[64 * 72];
  __shared__ unsigned short Wtl[64 * 72];
  const int t = threadIdx.x;
  const int rowBase = blockIdx.y * 64;
  const int colBase = blockIdx.x * 64;

  for (int idx = t; idx < 384; idx += 256) W1s[idx >> 6][idx & 63] = W1[idx];
  if (t < 64) b1s[t] = b1[t];
  {
    const int colloc = t >> 2, kq = (t & 3) * 16;
    const size_t src = (size_t)(colBase + colloc) * 64 + kq;
    *(uint4*)&Wth[colloc * 72 + kq] = *(const uint4*)&W2th[src];
    *(uint4*)&Wth[colloc * 72 + kq + 8] = *(const uint4*)&W2th[src + 8];
    *(uint4*)&Wtl[colloc * 72 + kq] = *(const uint4*)&W2tl[src];
    *(uint4*)&Wtl[colloc * 72 + kq + 8] = *(const uint4*)&W2tl[src + 8];
  }
  if (t < 64) {
    int e = rowBase + t;
    int i = e >> 3;
    int j = nbr[e];
    float xi0 = pts[i * 3], xi1 = pts[i * 3 + 1], xi2 = pts[i * 3 + 2];
    es[t][0] = xi0;
    es[t][1] = xi1;
    es[t][2] = xi2;
    es[t][3] = pts[j * 3] - xi0;
    es[t][4] = pts[j * 3 + 1] - xi1;
    es[t][5] = pts[j * 3 + 2] - xi2;
  }
  __syncthreads();

  {
    const int e = t & 63, k0 = (t >> 6) * 16;
    const float f0 = es[e][0], f1 = es[e][1], f2 = es[e][2];
    const float f3 = es[e][3], f4 = es[e][4], f5 = es[e][5];
    float h[16];
#pragma unroll
    for (int k = 0; k < 16; ++k) {
      int c = k0 + k;
      float v = b1s[c];
      v = fmaf(f0, W1s[0][c], v);
      v = fmaf(f1, W1s[1][c], v);
      v = fmaf(f2, W1s[2][c], v);
      v = fmaf(f3, W1s[3][c], v);
      v = fmaf(f4, W1s[4][c], v);
      v = fmaf(f5, W1s[5][c], v);
      h[k] = fmaxf(v, 0.0f);
    }
    unsigned int hp[8], lp[8];
#pragma unroll
    for (int u = 0; u < 8; ++u) {
      unsigned short h0 = f2bf(h[2 * u]), h1 = f2bf(h[2 * u + 1]);
      hp[u] = (unsigned int)h0 | ((unsigned int)h1 << 16);
      unsigned short l0 = f2bf(h[2 * u] - bf2f(h0));
      unsigned short l1 = f2bf(h[2 * u + 1] - bf2f(h1));
      lp[u] = (unsigned int)l0 | ((unsigned int)l1 << 16);
    }
    *(uint4*)&H1h[e * 72 + k0] = make_uint4(hp[0], hp[1], hp[2], hp[3]);
    *(uint4*)&H1h[e * 72 + k0 + 8] = make_uint4(hp[4], hp[5], hp[6], hp[7]);
    *(uint4*)&H1l[e * 72 + k0] = make_uint4(lp[0], lp[1], lp[2], lp[3]);
    *(uint4*)&H1l[e * 72 + k0 + 8] = make_uint4(lp[4], lp[5], lp[6], lp[7]);
  }
  __syncthreads();

  const int lane = t & 63, w = t >> 6;
  const int qq = lane >> 4, nidx = lane & 15;
  f32x4 acc[4];
#pragma unroll
  for (int nt = 0; nt < 4; ++nt) acc[nt] = (f32x4){0.f, 0.f, 0.f, 0.f};
  bf16x8 ah0, ah1, al0, al1;
  {
    const int row = w * 16 + nidx;
    ah0 = *(const bf16x8*)&H1h[row * 72 + qq * 8];
    ah1 = *(const bf16x8*)&H1h[row * 72 + 32 + qq * 8];
    al0 = *(const bf16x8*)&H1l[row * 72 + qq * 8];
    al1 = *(const bf16x8*)&H1l[row * 72 + 32 + qq * 8];
  }
#pragma unroll
  for (int nt = 0; nt < 4; ++nt) {
    const int col = nt * 16 + nidx;
    bf16x8 bh0 = *(const bf16x8*)&Wth[col * 72 + qq * 8];
    bf16x8 bh1 = *(const bf16x8*)&Wth[col * 72 + 32 + qq * 8];
    bf16x8 bl0 = *(const bf16x8*)&Wtl[col * 72 + qq * 8];
    bf16x8 bl1 = *(const bf16x8*)&Wtl[col * 72 + 32 + qq * 8];
    acc[nt] = __builtin_amdgcn_mfma_f32_16x16x32_bf16(ah0, bh0, acc[nt], 0, 0, 0);
    acc[nt] = __builtin_amdgcn_mfma_f32_16x16x32_bf16(ah1, bh1, acc[nt], 0, 0, 0);
    acc[nt] = __builtin_amdgcn_mfma_f32_16x16x32_bf16(ah0, bl0, acc[nt], 0, 0, 0);
    acc[nt] = __builtin_amdgcn_mfma_f32_16x16x32_bf16(ah1, bl1, acc[nt], 0, 0, 0);
    acc[nt] = __builtin_amdgcn_mfma_f32_16x16x32_bf16(al0, bh0, acc[nt], 0, 0, 0);
    acc[nt] = __builtin_amdgcn_mfma_f32_16x16x32_bf16(al1, bh1, acc[nt], 0, 0, 0);
  }

  const int pt = blockIdx.y * 8 + 2 * w + (qq >> 1);
#pragma unroll
  for (int nt = 0; nt < 4; ++nt) {
    f32x4 a = acc[nt];
    float m = fmaxf(fmaxf(a[0], a[1]), fmaxf(a[2], a[3]));
    float o = fmaxf(m, __shfl_xor(m, 16, 64));
    if ((qq & 1) == 0) {
      int cg = colBase + nt * 16 + nidx;
      y[(size_t)pt * 128 + cg] = fmaxf(o + b2[cg], 0.0f);
    }
  }
}

// ---------------------------------------------------------------------------
// AC = y @ Wcat (+b3 on cols<128) via split-bf16 3-pass MFMA (gemm2's
// verified structure: same LDS strides, fragment indexing, C/D mapping).
// 128 rows x 128 cols per block; K=128 in 4 chunks of 32; y split to bf16
// hi/lo in-kernel (as gemm2 does for H2); B copied from prep's W3t.
// ---------------------------------------------------------------------------
__global__ __launch_bounds__(256) void gemm_ac_mfma_kernel(
    const float* __restrict__ y, const unsigned short* __restrict__ W3th,
    const unsigned short* __restrict__ W3tl, const float* __restrict__ bias,
    float* __restrict__ AC) {
  __shared__ unsigned short Ah[128 * 40];
  __shared__ unsigned short Al[128 * 40];
  __shared__ unsigned short Bh[128 * 40];
  __shared__ unsigned short Bl[128 * 40];
  const int t = threadIdx.x;
  const int rowBase = blockIdx.y * 128;
  const int colBase = blockIdx.x * 128;
  const int eloc = t >> 1, hh = t & 1;
  const int kb = hh * 16;
  const int lane = t & 63, w = t >> 6;
  const int q = lane >> 4, nidx = lane & 15;

  f32x4 acc[2][8];
#pragma unroll
  for (int mt = 0; mt < 2; ++mt)
#pragma unroll
    for (int nt = 0; nt < 8; ++nt) acc[mt][nt] = (f32x4){0.f, 0.f, 0.f, 0.f};

  for (int p = 0; p < 4; ++p) {
    const int k0 = p * 32;
    {
      // A stage: y row -> bf16 hi/lo (same split pattern as gemm2's H2).
      const float* src = &y[(size_t)(rowBase + eloc) * 128 + k0 + kb];
      float h[16];
      *(float4*)&h[0] = *(const float4*)&src[0];
      *(float4*)&h[4] = *(const float4*)&src[4];
      *(float4*)&h[8] = *(const float4*)&src[8];
      *(float4*)&h[12] = *(const float4*)&src[12];
      unsigned int hp[8], lp[8];
#pragma unroll
      for (int u = 0; u < 8; ++u) {
        unsigned short h0 = f2bf(h[2 * u]), h1 = f2bf(h[2 * u + 1]);
        hp[u] = (unsigned int)h0 | ((unsigned int)h1 << 16);
        unsigned short l0 = f2bf(h[2 * u] - bf2f(h0));
        unsigned short l1 = f2bf(h[2 * u + 1] - bf2f(h1));
        lp[u] = (unsigned int)l0 | ((unsigned int)l1 << 16);
      }
      *(uint4*)&Ah[eloc * 40 + kb] = make_uint4(hp[0], hp[1], hp[2], hp[3]);
      *(uint4*)&Ah[eloc * 40 + kb + 8] = make_uint4(hp[4], hp[5], hp[6], hp[7]);
      *(uint4*)&Al[eloc * 40 + kb] = make_uint4(lp[0], lp[1], lp[2], lp[3]);
      *(uint4*)&Al[eloc * 40 + kb + 8] = make_uint4(lp[4], lp[5], lp[6], lp[7]);
    }
    {
      const size_t src = (size_t)(colBase + eloc) * 128 + k0 + kb;
      *(uint4*)&Bh[eloc * 40 + kb] = *(const uint4*)&W3th[src];
      *(uint4*)&Bh[eloc * 40 + kb + 8] = *(const uint4*)&W3th[src + 8];
      *(uint4*)&Bl[eloc * 40 + kb] = *(const uint4*)&W3tl[src];
      *(uint4*)&Bl[eloc * 40 + kb + 8] = *(const uint4*)&W3tl[src + 8];
    }
    __syncthreads();
    bf16x8 ah[2], al[2];
#pragma unroll
    for (int mt = 0; mt < 2; ++mt) {
      int row = w * 32 + mt * 16 + nidx;
      ah[mt] = *(const bf16x8*)&Ah[row * 40 + q * 8];
      al[mt] = *(const bf16x8*)&Al[row * 40 + q * 8];
    }
#pragma unroll
    for (int nt = 0; nt < 8; ++nt) {
      int col = nt * 16 + nidx;
      bf16x8 bh = *(const bf16x8*)&Bh[col * 40 + q * 8];
      bf16x8 bl = *(const bf16x8*)&Bl[col * 40 + q * 8];
#pragma unroll
      for (int mt = 0; mt < 2; ++mt) {
        acc[mt][nt] = __builtin_amdgcn_mfma_f32_16x16x32_bf16(
            ah[mt], bh, acc[mt][nt], 0, 0, 0);
        acc[mt][nt] = __builtin_amdgcn_mfma_f32_16x16x32_bf16(
            ah[mt], bl, acc[mt][nt], 0, 0, 0);
        acc[mt][nt] = __builtin_amdgcn_mfma_f32_16x16x32_bf16(
            al[mt], bh, acc[mt][nt], 0, 0, 0);
      }
    }
    __syncthreads();
  }

  // Epilogue: C/D row = q*4+reg within the 16-row frag; col = nt*16+nidx.
#pragma unroll
  for (int mt = 0; mt < 2; ++mt) {
    const int rowb = rowBase + w * 32 + mt * 16 + q * 4;
#pragma unroll
    for (int nt = 0; nt < 8; ++nt) {
      f32x4 a = acc[mt][nt];
      const int cg = colBase + nt * 16 + nidx;
      const float bb = (cg < 128) ? bias[cg] : 0.0f;
#pragma unroll
      for (int reg = 0; reg < 4; ++reg) {
        AC[(size_t)(rowb + reg) * 256 + cg] = a[reg] + bb;
      }
    }
  }
}

// ---------------------------------------------------------------------------
// MFMA EdgeConv2 second layer (split-bf16), as R7 (verified):
// D = Hh*Wh + Hh*Wl + Hl*Wh in fp32 MFMA acc; in-register segmax + b4.
// ---------------------------------------------------------------------------
__global__ __launch_bounds__(256) void gemm2_mfma_kernel(
    const float* __restrict__ AC, const int* __restrict__ nbr,
    const unsigned short* __restrict__ W4ht,
    const unsigned short* __restrict__ W4lt, const float* __restrict__ b4,
    float* __restrict__ out) {
  __shared__ unsigned short H2h[128 * 40];
  __shared__ unsigned short H2l[128 * 40];
  __shared__ unsigned short Wth[128 * 40];
  __shared__ unsigned short Wtl[128 * 40];
  const int t = threadIdx.x;
  const int rowBase = blockIdx.y * 128;
  const int colBase = blockIdx.x * 128;
  const int eloc = t >> 1, hh = t & 1;
  const int kb = hh * 16;
  const int edge = rowBase + eloc;
  const int ip = edge >> 3;
  const int jp = nbr[edge];
  const float* ai_p = AC + (size_t)ip * 256;
  const float* ci_p = ai_p + 128;
  const float* cj_p = AC + (size_t)jp * 256 + 128;
  const int lane = t & 63;
  const int w = t >> 6;
  const int q = lane >> 4;
  const int nidx = lane & 15;

  f32x4 acc[2][8];
#pragma unroll
  for (int mt = 0; mt < 2; ++mt)
#pragma unroll
    for (int nt = 0; nt < 8; ++nt) acc[mt][nt] = (f32x4){0.f, 0.f, 0.f, 0.f};

  for (int p = 0; p < 4; ++p) {
    const int k0 = p * 32;
    {
      float h2[16];
      const float4* a4 = (const float4*)(ai_p + k0 + kb);
      const float4* c4 = (const float4*)(ci_p + k0 + kb);
      const float4* d4 = (const float4*)(cj_p + k0 + kb);
#pragma unroll
      for (int u = 0; u < 4; ++u) {
        float4 a = a4[u], c = c4[u], d = d4[u];
        h2[u * 4 + 0] = fmaxf(a.x + d.x - c.x, 0.f);
        h2[u * 4 + 1] = fmaxf(a.y + d.y - c.y, 0.f);
        h2[u * 4 + 2] = fmaxf(a.z + d.z - c.z, 0.f);
        h2[u * 4 + 3] = fmaxf(a.w + d.w - c.w, 0.f);
      }
      unsigned int hp[8], lp[8];
#pragma unroll
      for (int u = 0; u < 8; ++u) {
        unsigned short h0 = f2bf(h2[2 * u]), h1 = f2bf(h2[2 * u + 1]);
        hp[u] = (unsigned int)h0 | ((unsigned int)h1 << 16);
        unsigned short l0 = f2bf(h2[2 * u] - bf2f(h0));
        unsigned short l1 = f2bf(h2[2 * u + 1] - bf2f(h1));
        lp[u] = (unsigned int)l0 | ((unsigned int)l1 << 16);
      }
      *(uint4*)&H2h[eloc * 40 + kb] = make_uint4(hp[0], hp[1], hp[2], hp[3]);
      *(uint4*)&H2h[eloc * 40 + kb + 8] =
          make_uint4(hp[4], hp[5], hp[6], hp[7]);
      *(uint4*)&H2l[eloc * 40 + kb] = make_uint4(lp[0], lp[1], lp[2], lp[3]);
      *(uint4*)&H2l[eloc * 40 + kb + 8] =
          make_uint4(lp[4], lp[5], lp[6], lp[7]);
    }
    {
      const size_t src = (size_t)(colBase + eloc) * 128 + k0 + kb;
      *(uint4*)&Wth[eloc * 40 + kb] = *(const uint4*)&W4ht[src];
      *(uint4*)&Wth[eloc * 40 + kb + 8] = *(const uint4*)&W4ht[src + 8];
      *(uint4*)&Wtl[eloc * 40 + kb] = *(const uint4*)&W4lt[src];
      *(uint4*)&Wtl[eloc * 40 + kb + 8] = *(const uint4*)&W4lt[src + 8];
    }
    __syncthreads();
    bf16x8 ah[2], al[2];
#pragma unroll
    for (int mt = 0; mt < 2; ++mt) {
      int row = w * 32 + mt * 16 + nidx;
      ah[mt] = *(const bf16x8*)&H2h[row * 40 + q * 8];
      al[mt] = *(const bf16x8*)&H2l[row * 40 + q * 8];
    }
#pragma unroll
    for (int nt = 0; nt < 8; ++nt) {
      int col = nt * 16 + nidx;
      bf16x8 bh = *(const bf16x8*)&Wth[col * 40 + q * 8];
      bf16x8 bl = *(const bf16x8*)&Wtl[col * 40 + q * 8];
#pragma unroll
      for (int mt = 0; mt < 2; ++mt) {
        acc[mt][nt] = __builtin_amdgcn_mfma_f32_16x16x32_bf16(
            ah[mt], bh, acc[mt][nt], 0, 0, 0);
        acc[mt][nt] = __builtin_amdgcn_mfma_f32_16x16x32_bf16(
            ah[mt], bl, acc[mt][nt], 0, 0, 0);
        acc[mt][nt] = __builtin_amdgcn_mfma_f32_16x16x32_bf16(
            al[mt], bh, acc[mt][nt], 0, 0, 0);
      }
    }
    __syncthreads();
  }

#pragma unroll
  for (int mt = 0; mt < 2; ++mt) {
    const int ebase = rowBase + w * 32 + mt * 16;
    const int pt0 = ebase >> 3;
#pragma unroll
    for (int nt = 0; nt < 8; ++nt) {
      f32x4 a = acc[mt][nt];
      float m = fmaxf(fmaxf(a[0], a[1]), fmaxf(a[2], a[3]));
      float o = fmaxf(m, __shfl_xor(m, 16, 64));
      int cg = colBase + nt * 16 + nidx;
      if (q == 0) {
        out[(size_t)pt0 * 256 + cg] = o + b4[cg];
      } else if (q == 2) {
        out[(size_t)(pt0 + 1) * 256 + cg] = o + b4[cg];
      }
    }
  }
}

extern "C" void kernel_launch(void* const* d_in, const int* in_sizes, int n_in,
                              void* d_out, int out_size, void* d_ws,
                              size_t ws_size, hipStream_t stream) {
  const float* pts = (const float*)d_in[0];
  const float* W1 = (const float*)d_in[1];
  const float* b1 = (const float*)d_in[2];
  const float* W2 = (const float*)d_in[3];
  const float* b2 = (const float*)d_in[4];
  const float* W3 = (const float*)d_in[5];
  const float* b3 = (const float*)d_in[6];
  const float* W4 = (const float*)d_in[7];
  const float* b4 = (const float*)d_in[8];
  float* out = (float*)d_out;

  // Workspace layout (floats), lifetime-overlapped:
  //   part_v [0, 1048576)          : vals->thresh (within AC region)
  //   thr    [4194304, +8192)      : thresh->collect
  //   nbr    [4202496, +65536)     : collect->gemm1/gemm2
  //   y      [4268032, +1048576)   : gemm1->gemm_ac
  //   mask   [5316608, +16384)     : thresh->collect (u64[8192])
  //   W4ht   [5332992, +16384)
  //   W4lt   [5349376, +16384)
  //   pts4   [5365760, +32768)     : prep->vals/collect (f4[8192])
  //   W2th   [5398528, +4096)      : prep->gemm1 (ushort[8192])
  //   W2tl   [5402624, +4096)      : prep->gemm1 (ushort[8192])
  //   W3th   [5406720, +16384)     : prep->gemm_ac (ushort[32768])
  //   W3tl   [5423104, +16384)     : prep->gemm_ac (ushort[32768])
  //   AC = [0, 2097152) (written after part_v is dead)
  float* w = (float*)d_ws;
  float* part_v = w;
  float* thr = w + 4194304;
  int* nbr = (int*)(w + 4202496);
  float* y = w + 4268032;
  unsigned long long* mask = (unsigned long long*)(w + 5316608);
  unsigned short* W4ht = (unsigned short*)(w + 5332992);
  unsigned short* W4lt = (unsigned short*)(w + 5349376);
  float4* pts4 = (float4*)(w + 5365760);
  unsigned short* W2th = (unsigned short*)(w + 5398528);
  unsigned short* W2tl = (unsigned short*)(w + 5402624);
  unsigned short* W3th = (unsigned short*)(w + 5406720);
  unsigned short* W3tl = (unsigned short*)(w + 5423104);
  float* AC = w;

  // 0. Prep: W4/Wcat bf16-splits + pts4 pack + W2 transpose-split (fused).
  prep_kernel<<<128, 256, 0, stream>>>(W4, pts, W2, W3, W4ht, W4lt, W2th,
                                       W2tl, W3th, W3tl, pts4);

  // 1. KNN: slice top-2 values -> parallel pool-merge thresh -> collect.
  knn_vals_kernel<<<dim3(32, NSLICE), 256, 0, stream>>>(pts4, part_v);
  knn_thresh_kernel<<<NPTS / TQ, 256, 0, stream>>>(part_v, thr, mask);
  knn_collect_kernel<<<2048, 256, 0, stream>>>(pts4, thr, mask, nbr);

  // 2. EdgeConv1 (MFMA H1@W2 + max8 + b2 + relu)
  gemm1_fused_kernel<<<dim3(2, 1024), 256, 0, stream>>>(pts, nbr, W1, b1,
                                                        W2th, W2tl, b2, y);

  // 3. EdgeConv2: AC = y@Wcat (+b3) via MFMA, then MFMA H2+GEMM+max8+b4.
  gemm_ac_mfma_kernel<<<dim3(2, 64), 256, 0, stream>>>(y, W3th, W3tl, b3, AC);
  gemm2_mfma_kernel<<<dim3(2, 512), 256, 0, stream>>>(AC, nbr, W4ht, W4lt, b4,
                                                      out);
}